// Round 15
// baseline (1869.820 us; speedup 1.0000x reference)
//
#include <hip/hip_runtime.h>
#include <hip/hip_bf16.h>
#include <hip/hip_fp16.h>

// Problem constants (fixed by the reference)
#define N_ 100000
#define MPAD 100096          // 782 * 128
#define E_ 400000
#define B_ 2048
#define H_ 300
#define KP_ 320              // H padded to mult of 32
#define L_ 5
#define EF_ 16
#define T_ 128
#define ANODES 16            // nodes per k_agg block (6250 blocks)
#define EMAX 256             // LDS-staged edge capacity per block (mean cnt=64)
#define BNS 0.9999950000374997f  // 1/sqrt(1+1e-5)

typedef unsigned short ushort_t;
typedef short bf16x8 __attribute__((ext_vector_type(8)));
typedef float f32x4 __attribute__((ext_vector_type(4)));
typedef _Float16 h2f __attribute__((ext_vector_type(2)));

__device__ __forceinline__ ushort_t f2b(float v) {
    unsigned u = __float_as_uint(v);
    unsigned r = (u + 0x7FFFu + ((u >> 16) & 1u)) >> 16;
    return (ushort_t)r;
}

__device__ __forceinline__ float b2f(ushort_t u) {
    return __uint_as_float(((unsigned)u) << 16);
}

__device__ __forceinline__ void gl_lds16(const void* g, void* l) {
    __builtin_amdgcn_global_load_lds(
        (const __attribute__((address_space(1))) void*)g,
        (__attribute__((address_space(3))) void*)l, 16, 0, 0);
}

// swizzled column for logical (row r, col j) in a swizzled bf16 buffer
__device__ __forceinline__ int swzcol(int r, int j) {
    int u = ((j >> 3) & 3) ^ ((r >> 1) & 3);
    return (j & ~31) | (u << 3) | (j & 7);
}

// ---------------- CSR build ----------------
__global__ void k_hist(const int* __restrict__ dst, int* __restrict__ degi, int E) {
    int e = blockIdx.x * blockDim.x + threadIdx.x;
    if (e < E) atomicAdd(&degi[dst[e]], 1);
}

__global__ void k_norm(const int* __restrict__ degi, float* __restrict__ nrm,
                       float* __restrict__ invdeg, int N) {
    int n = blockIdx.x * blockDim.x + threadIdx.x;
    if (n < N) {
        float d = (float)degi[n] + 1.0f;
        nrm[n] = 1.0f / sqrtf(d);
        invdeg[n] = 1.0f / d;
    }
}

__global__ void k_scan1(const int* __restrict__ in, int* __restrict__ out,
                        int* __restrict__ partial, int N) {
    __shared__ int s[1024];
    int i = blockIdx.x * 1024 + threadIdx.x;
    int v = (i < N) ? in[i] : 0;
    s[threadIdx.x] = v;
    __syncthreads();
    for (int off = 1; off < 1024; off <<= 1) {
        int t = (threadIdx.x >= off) ? s[threadIdx.x - off] : 0;
        __syncthreads();
        s[threadIdx.x] += t;
        __syncthreads();
    }
    if (i < N) out[i] = s[threadIdx.x] - v;  // exclusive
    if (threadIdx.x == 1023) partial[blockIdx.x] = s[1023];
}

__global__ void k_scan2(int* __restrict__ partial, int nb, int* __restrict__ totalOut) {
    __shared__ int sh[128];
    int t = threadIdx.x;
    int v = (t < nb) ? partial[t] : 0;
    sh[t] = v;
    __syncthreads();
    for (int off = 1; off < 128; off <<= 1) {
        int u = (t >= off) ? sh[t - off] : 0;
        __syncthreads();
        sh[t] += u;
        __syncthreads();
    }
    if (t < nb) partial[t] = sh[t] - v;  // exclusive
    if (t == 127) *totalOut = sh[127];
}

__global__ void k_scan3(int* __restrict__ out, const int* __restrict__ partial, int N) {
    int i = blockIdx.x * 1024 + threadIdx.x;
    if (i < N) out[i] += partial[blockIdx.x];
}

// scatter edges into CSR order; meta = (src*KP_, en bits); f16 edge feats
__global__ void k_scatter(const int* __restrict__ dst, const int* __restrict__ src,
                          const float* __restrict__ ef, const float* __restrict__ nrm,
                          int* __restrict__ cursor, int2* __restrict__ meta,
                          ushort_t* __restrict__ ef16, int E) {
    int e = blockIdx.x * blockDim.x + threadIdx.x;
    if (e >= E) return;
    int d = dst[e], s = src[e];
    int pos = atomicAdd(&cursor[d], 1);
    int2 md;
    md.x = s * KP_;
    md.y = __float_as_int(nrm[s] * nrm[d]);
    meta[pos] = md;
    const float4* ep = (const float4*)&ef[(size_t)e * EF_];
    float4 e0 = ep[0], e1 = ep[1], e2 = ep[2], e3 = ep[3];
    uint4 ua, ub;
    ua.x = __builtin_bit_cast(unsigned, __floats2half2_rn(e0.x, e0.y));
    ua.y = __builtin_bit_cast(unsigned, __floats2half2_rn(e0.z, e0.w));
    ua.z = __builtin_bit_cast(unsigned, __floats2half2_rn(e1.x, e1.y));
    ua.w = __builtin_bit_cast(unsigned, __floats2half2_rn(e1.z, e1.w));
    ub.x = __builtin_bit_cast(unsigned, __floats2half2_rn(e2.x, e2.y));
    ub.y = __builtin_bit_cast(unsigned, __floats2half2_rn(e2.z, e2.w));
    ub.z = __builtin_bit_cast(unsigned, __floats2half2_rn(e3.x, e3.y));
    ub.w = __builtin_bit_cast(unsigned, __floats2half2_rn(e3.z, e3.w));
    uint4* op = (uint4*)&ef16[(size_t)pos * 16];
    op[0] = ua; op[1] = ub;
}

__global__ void k_rowstart(const int* __restrict__ gid, int* __restrict__ rs, int N, int B) {
    int b = blockIdx.x * blockDim.x + threadIdx.x;
    if (b <= B) {
        int lo = 0, hi = N;
        while (lo < hi) { int mid = (lo + hi) >> 1; if (gid[mid] < b) lo = mid + 1; else hi = mid; }
        rs[b] = lo;
    }
}

// ---------------- init ----------------
// writes ALL 320 cols (pad cols = 0) so later vector reads of pads are safe
__global__ void k_hinit(const int* __restrict__ nt, const float* __restrict__ emb,
                        const float* __restrict__ vn_emb,
                        ushort_t* __restrict__ h_bf) {
    int n = blockIdx.x; int j = threadIdx.x;
    if (j >= KP_) return;
    float v = (j < H_) ? emb[(size_t)nt[n] * H_ + j] + vn_emb[j] : 0.f;
    h_bf[(size_t)n * KP_ + swzcol(n, j)] = f2b(v);
}

__global__ void k_vninit(const float* __restrict__ vn_emb, float* __restrict__ vn) {
    int b = blockIdx.x; int j = threadIdx.x;
    if (j >= H_) return;
    vn[(size_t)b * H_ + j] = vn_emb[j];
}

// weight conversion: WT[l][n][k] = W[l][k][n], bf16, zero-padded, row-swizzled
__global__ void k_convW(const float* __restrict__ W, ushort_t* __restrict__ WT,
                        int nl, int K, int Nout, int KPv, int NPBv) {
    int UPR = KPv / 8;
    int tot = nl * NPBv * UPR;
    int idx = blockIdx.x * 256 + threadIdx.x;
    if (idx >= tot) return;
    int l = idx / (NPBv * UPR); int r = idx % (NPBv * UPR);
    int n = r / UPR; int ku = r % UPR;
    int k0 = ku * 8;
    int swz = (ku & 3) ^ ((n >> 1) & 3);
    size_t d = ((size_t)l * NPBv + n) * KPv + (size_t)(k0 & ~31) + swz * 8;
    #pragma unroll
    for (int i = 0; i < 8; i++) {
        int k = k0 + i;
        float v = (k < K && n < Nout) ? W[((size_t)l * K + k) * Nout + n] : 0.f;
        WT[d + i] = f2b(v);
    }
}

// We -> packed half2 pairs: Weh[l][k2][j] = (We[l][2k2][j], We[l][2k2+1][j])
__global__ void k_convWeh(const float* __restrict__ We, unsigned* __restrict__ Weh) {
    int idx = blockIdx.x * 256 + threadIdx.x;
    if (idx >= L_ * 8 * H_) return;
    int l = idx / (8 * H_); int r = idx % (8 * H_);
    int k2 = r / H_; int j = r % H_;
    float a = We[((size_t)l * EF_ + 2 * k2) * H_ + j];
    float b = We[((size_t)l * EF_ + 2 * k2 + 1) * H_ + j];
    Weh[((size_t)l * 8 + k2) * H_ + j] = __builtin_bit_cast(unsigned, __floats2half2_rn(a, b));
}

// ---------------- unified bf16 MFMA GEMM ----------------
// NOTE: blockIdx.x = N-block (few), blockIdx.y = M-block (many) so consecutive
// blocks share the same A panel via L2 (XCD-friendly ordering).
#define MB 128
#define NB 128
__launch_bounds__(256)
__global__ void k_bgemm(const ushort_t* __restrict__ A, const ushort_t* __restrict__ BT,
                        int M, int Nn, int KP,
                        const float* __restrict__ bias, const float* __restrict__ scale,
                        const float* __restrict__ shift, int relu,
                        float* __restrict__ Cf, int ldf,
                        ushort_t* __restrict__ Cb, int ldb, int swzout) {
    __shared__ ushort_t As[MB * 32];
    __shared__ ushort_t Bs[NB * 32];
    int tid = threadIdx.x;
    int lane = tid & 63, wid = tid >> 6;
    int wm = wid >> 1, wn = wid & 1;
    int m0 = blockIdx.y * MB, n0 = blockIdx.x * NB;
    f32x4 acc[4][4];
    #pragma unroll
    for (int mi = 0; mi < 4; mi++)
        #pragma unroll
        for (int ni = 0; ni < 4; ni++)
            acc[mi][ni] = (f32x4){0.f, 0.f, 0.f, 0.f};

    const ushort_t* Ab = A + (size_t)m0 * KP;
    const ushort_t* Bb = BT + (size_t)n0 * KP;
    int lr = lane & 15, lg = lane >> 4;

    for (int k0 = 0; k0 < KP; k0 += 32) {
        #pragma unroll
        for (int i = 0; i < 2; i++) {
            int li = tid + 256 * i;
            int r = li >> 2, u = li & 3;
            gl_lds16(Ab + (size_t)r * KP + k0 + u * 8, &As[(size_t)(li & ~63) * 8]);
        }
        #pragma unroll
        for (int i = 0; i < 2; i++) {
            int li = tid + 256 * i;
            int r = li >> 2, u = li & 3;
            gl_lds16(Bb + (size_t)r * KP + k0 + u * 8, &Bs[(size_t)(li & ~63) * 8]);
        }
        __syncthreads();
        bf16x8 af[4], bv[4];
        #pragma unroll
        for (int mi = 0; mi < 4; mi++) {
            int rr = wm * 64 + mi * 16 + lr;
            int uu = lg ^ ((rr >> 1) & 3);
            af[mi] = *(const bf16x8*)&As[rr * 32 + uu * 8];
        }
        #pragma unroll
        for (int ni = 0; ni < 4; ni++) {
            int rr = wn * 64 + ni * 16 + lr;
            int uu = lg ^ ((rr >> 1) & 3);
            bv[ni] = *(const bf16x8*)&Bs[rr * 32 + uu * 8];
        }
        #pragma unroll
        for (int mi = 0; mi < 4; mi++)
            #pragma unroll
            for (int ni = 0; ni < 4; ni++)
                acc[mi][ni] = __builtin_amdgcn_mfma_f32_16x16x32_bf16(
                    af[mi], bv[ni], acc[mi][ni], 0, 0, 0);
        __syncthreads();
    }

    #pragma unroll
    for (int ni = 0; ni < 4; ni++) {
        int gn = n0 + wn * 64 + ni * 16 + lr;
        if (gn >= Nn) continue;
        float bvv = bias[gn];
        float sc = scale ? scale[gn] * BNS : 0.f;
        float sh = shift ? shift[gn] : 0.f;
        #pragma unroll
        for (int mi = 0; mi < 4; mi++) {
            #pragma unroll
            for (int t = 0; t < 4; t++) {
                int gm = m0 + wm * 64 + mi * 16 + lg * 4 + t;
                if (gm >= M) continue;
                float v = acc[mi][ni][t] + bvv;
                if (scale) v = v * sc + sh;
                if (relu) v = fmaxf(v, 0.f);
                if (Cf) Cf[(size_t)gm * ldf + gn] = v;
                else    Cb[(size_t)gm * ldb + (swzout ? swzcol(gm, gn) : gn)] = f2b(v);
            }
        }
    }
}

// ---------------- vectorized per-graph segment sum -> vtmp (swizzled bf16) ----------------
__launch_bounds__(256)
__global__ void k_vtmp(const ushort_t* __restrict__ h_bf, const float* __restrict__ vn,
                       const int* __restrict__ rs, ushort_t* __restrict__ vtmp_bf) {
    __shared__ float red[40 * 8 * 6];
    int b = blockIdx.x;
    int t = threadIdx.x;
    int u = t % 40, rr = t / 40;
    int s = rs[b], e = rs[b + 1];
    if (rr < 6) {
        float a8[8] = {0.f, 0.f, 0.f, 0.f, 0.f, 0.f, 0.f, 0.f};
        int g = u >> 2, w = u & 3;
        for (int n = s + rr; n < e; n += 6) {
            int phys = (g << 2) | (w ^ ((n >> 1) & 3));
            bf16x8 hv = *(const bf16x8*)&h_bf[(size_t)n * KP_ + phys * 8];
            #pragma unroll
            for (int k = 0; k < 8; k++) a8[k] += b2f((ushort_t)hv[k]);
        }
        #pragma unroll
        for (int k = 0; k < 8; k++) red[(u * 8 + k) * 6 + rr] = a8[k];
    }
    __syncthreads();
    if (t < 40) {
        int g = t >> 2, w = t & 3;
        int phys = (g << 2) | (w ^ ((b >> 1) & 3));
        ushort_t ov[8];
        #pragma unroll
        for (int k = 0; k < 8; k++) {
            int j = t * 8 + k;
            float sum = 0.f;
            #pragma unroll
            for (int r = 0; r < 6; r++) sum += red[(t * 8 + k) * 6 + r];
            float val = (j < H_) ? sum + vn[(size_t)b * H_ + j] : 0.f;
            ov[k] = f2b(val);
        }
        *(bf16x8*)&vtmp_bf[(size_t)b * KP_ + phys * 8] = *(bf16x8*)ov;
    }
}

// ---------------- vectorized fused readout: gmean -> head ----------------
__launch_bounds__(256)
__global__ void k_readout(const ushort_t* __restrict__ h_bf, const int* __restrict__ rs,
                          const float* __restrict__ pW, const float* __restrict__ pb,
                          float* __restrict__ out) {
    __shared__ float red[40 * 8 * 6];
    __shared__ float gg[320];
    int b = blockIdx.x;
    int t = threadIdx.x;
    int u = t % 40, rr = t / 40;
    int s = rs[b], e = rs[b + 1];
    if (rr < 6) {
        float a8[8] = {0.f, 0.f, 0.f, 0.f, 0.f, 0.f, 0.f, 0.f};
        int g = u >> 2, w = u & 3;
        for (int n = s + rr; n < e; n += 6) {
            int phys = (g << 2) | (w ^ ((n >> 1) & 3));
            bf16x8 hv = *(const bf16x8*)&h_bf[(size_t)n * KP_ + phys * 8];
            #pragma unroll
            for (int k = 0; k < 8; k++) a8[k] += b2f((ushort_t)hv[k]);
        }
        #pragma unroll
        for (int k = 0; k < 8; k++) red[(u * 8 + k) * 6 + rr] = a8[k];
    }
    __syncthreads();
    if (t < 40) {
        int cnt = e - s; if (cnt < 1) cnt = 1;
        float ic = 1.f / (float)cnt;
        #pragma unroll
        for (int k = 0; k < 8; k++) {
            float sum = 0.f;
            #pragma unroll
            for (int r = 0; r < 6; r++) sum += red[(t * 8 + k) * 6 + r];
            gg[t * 8 + k] = sum * ic;
        }
    }
    __syncthreads();
    if (t < T_) {
        float o = pb[t];
        #pragma unroll 4
        for (int k = 0; k < H_; k++) o = fmaf(gg[k], pW[(size_t)k * T_ + t], o);
        out[(size_t)b * T_ + t] = o;
    }
}

// ---------------- edge aggregation: 16 nodes/block, pair-interleaved streams ------------
__global__ void k_agg(const ushort_t* __restrict__ x_bf,
                      ushort_t* __restrict__ h_bf,
                      const int* __restrict__ off, const int2* __restrict__ meta,
                      const ushort_t* __restrict__ ef16,
                      const unsigned* __restrict__ Weh_l, const float* __restrict__ be_l,
                      const float* __restrict__ invdeg,
                      const float* __restrict__ root_l, const float* __restrict__ gamma_l,
                      const float* __restrict__ beta_l,
                      const float* __restrict__ vn_next, const int* __restrict__ gid,
                      int relu) {
    __shared__ int2 s_md[EMAX];
    __shared__ unsigned s_ef[EMAX * 8];
    int n0 = blockIdx.x * ANODES;
    int tid = threadIdx.x;
    int j = tid;

    int offv[ANODES + 1];
    #pragma unroll
    for (int k = 0; k <= ANODES; k++) offv[k] = off[n0 + k];
    int estart = offv[0], cnt = offv[ANODES] - estart;
    bool lds_ok = cnt <= EMAX;

    // stage edge metadata (coalesced; all threads)
    if (lds_ok) {
        const unsigned* efu = (const unsigned*)ef16;
        for (int t = tid; t < cnt; t += 320) s_md[t] = meta[estart + t];
        for (int uu = tid; uu < 8 * cnt; uu += 320)
            s_ef[uu] = efu[(size_t)estart * 8 + uu];
    }
    __syncthreads();

    if (j >= H_) return;
    h2f wh[8];
    #pragma unroll
    for (int k2 = 0; k2 < 8; k2++)
        wh[k2] = __builtin_bit_cast(h2f, Weh_l[k2 * H_ + j]);
    float bej = be_l[j];

    // self x loads for all nodes (independent, issued early)
    float xn[ANODES];
    #pragma unroll
    for (int ln = 0; ln < ANODES; ln++)
        xn[ln] = b2f(x_bf[(size_t)(n0 + ln) * KP_ + j]);

    float accv[ANODES];
    #pragma unroll
    for (int k = 0; k < ANODES; k++) accv[k] = 0.f;

    if (lds_ok) {
        // pairs of node streams interleaved: up to 8 gathers in flight per iteration
        #pragma unroll
        for (int lp = 0; lp < ANODES / 2; lp++) {
            int na = 2 * lp, nb = 2 * lp + 1;
            int ia = offv[na] - estart, ea = offv[na + 1] - estart;
            int ib = offv[nb] - estart, eb = offv[nb + 1] - estart;
            float aa = 0.f, ab = 0.f;
            while (ia < ea || ib < eb) {  // wave-uniform condition
                bool qa = ia < ea, qb = ib < eb;
                // ---- issue phase ----
                int a0 = 0, a1 = 0, a2 = 0, a3 = 0;
                float ena0 = 0.f, ena1 = 0.f, ena2 = 0.f, ena3 = 0.f;
                float xa0 = 0.f, xa1 = 0.f, xa2 = 0.f, xa3 = 0.f;
                if (qa) {
                    a0 = ia;
                    a1 = (ia + 1 < ea) ? ia + 1 : ea - 1;
                    a2 = (ia + 2 < ea) ? ia + 2 : ea - 1;
                    a3 = (ia + 3 < ea) ? ia + 3 : ea - 1;
                    int2 m0 = s_md[a0], m1 = s_md[a1], m2 = s_md[a2], m3 = s_md[a3];
                    ena0 = __int_as_float(m0.y);
                    ena1 = (ia + 1 < ea) ? __int_as_float(m1.y) : 0.f;
                    ena2 = (ia + 2 < ea) ? __int_as_float(m2.y) : 0.f;
                    ena3 = (ia + 3 < ea) ? __int_as_float(m3.y) : 0.f;
                    xa0 = b2f(x_bf[(size_t)m0.x + j]);
                    xa1 = b2f(x_bf[(size_t)m1.x + j]);
                    xa2 = b2f(x_bf[(size_t)m2.x + j]);
                    xa3 = b2f(x_bf[(size_t)m3.x + j]);
                }
                int b0 = 0, b1 = 0, b2 = 0, b3 = 0;
                float enb0 = 0.f, enb1 = 0.f, enb2 = 0.f, enb3 = 0.f;
                float xb0 = 0.f, xb1 = 0.f, xb2 = 0.f, xb3 = 0.f;
                if (qb) {
                    b0 = ib;
                    b1 = (ib + 1 < eb) ? ib + 1 : eb - 1;
                    b2 = (ib + 2 < eb) ? ib + 2 : eb - 1;
                    b3 = (ib + 3 < eb) ? ib + 3 : eb - 1;
                    int2 m0 = s_md[b0], m1 = s_md[b1], m2 = s_md[b2], m3 = s_md[b3];
                    enb0 = __int_as_float(m0.y);
                    enb1 = (ib + 1 < eb) ? __int_as_float(m1.y) : 0.f;
                    enb2 = (ib + 2 < eb) ? __int_as_float(m2.y) : 0.f;
                    enb3 = (ib + 3 < eb) ? __int_as_float(m3.y) : 0.f;
                    xb0 = b2f(x_bf[(size_t)m0.x + j]);
                    xb1 = b2f(x_bf[(size_t)m1.x + j]);
                    xb2 = b2f(x_bf[(size_t)m2.x + j]);
                    xb3 = b2f(x_bf[(size_t)m3.x + j]);
                }
                // ---- compute phase ----
                if (qa) {
                    const unsigned* p0 = &s_ef[a0 * 8];
                    const unsigned* p1 = &s_ef[a1 * 8];
                    const unsigned* p2 = &s_ef[a2 * 8];
                    const unsigned* p3 = &s_ef[a3 * 8];
                    float e0 = bej, e1 = bej, e2 = bej, e3 = bej;
                    #pragma unroll
                    for (int k = 0; k < 8; k++) {
                        e0 = __builtin_amdgcn_fdot2(__builtin_bit_cast(h2f, p0[k]), wh[k], e0, false);
                        e1 = __builtin_amdgcn_fdot2(__builtin_bit_cast(h2f, p1[k]), wh[k], e1, false);
                        e2 = __builtin_amdgcn_fdot2(__builtin_bit_cast(h2f, p2[k]), wh[k], e2, false);
                        e3 = __builtin_amdgcn_fdot2(__builtin_bit_cast(h2f, p3[k]), wh[k], e3, false);
                    }
                    aa = fmaf(ena0, fmaxf(xa0 + e0, 0.f), aa);
                    aa = fmaf(ena1, fmaxf(xa1 + e1, 0.f), aa);
                    aa = fmaf(ena2, fmaxf(xa2 + e2, 0.f), aa);
                    aa = fmaf(ena3, fmaxf(xa3 + e3, 0.f), aa);
                    ia += 4;
                }
                if (qb) {
                    const unsigned* p0 = &s_ef[b0 * 8];
                    const unsigned* p1 = &s_ef[b1 * 8];
                    const unsigned* p2 = &s_ef[b2 * 8];
                    const unsigned* p3 = &s_ef[b3 * 8];
                    float e0 = bej, e1 = bej, e2 = bej, e3 = bej;
                    #pragma unroll
                    for (int k = 0; k < 8; k++) {
                        e0 = __builtin_amdgcn_fdot2(__builtin_bit_cast(h2f, p0[k]), wh[k], e0, false);
                        e1 = __builtin_amdgcn_fdot2(__builtin_bit_cast(h2f, p1[k]), wh[k], e1, false);
                        e2 = __builtin_amdgcn_fdot2(__builtin_bit_cast(h2f, p2[k]), wh[k], e2, false);
                        e3 = __builtin_amdgcn_fdot2(__builtin_bit_cast(h2f, p3[k]), wh[k], e3, false);
                    }
                    ab = fmaf(enb0, fmaxf(xb0 + e0, 0.f), ab);
                    ab = fmaf(enb1, fmaxf(xb1 + e1, 0.f), ab);
                    ab = fmaf(enb2, fmaxf(xb2 + e2, 0.f), ab);
                    ab = fmaf(enb3, fmaxf(xb3 + e3, 0.f), ab);
                    ib += 4;
                }
            }
            accv[na] = aa;
            accv[nb] = ab;
        }
    } else {
        // rare fallback (cnt > EMAX): all-global path
        #pragma unroll
        for (int ln = 0; ln < ANODES; ln++) {
            int rel = offv[ln], rend = offv[ln + 1];
            float a = 0.f;
            for (int q = rel; q < rend; q++) {
                int2 m = meta[q];
                float xv = b2f(x_bf[(size_t)m.x + j]);
                const unsigned* eu = (const unsigned*)&ef16[(size_t)q * 16];
                float ev = bej;
                #pragma unroll
                for (int k = 0; k < 8; k++)
                    ev = __builtin_amdgcn_fdot2(__builtin_bit_cast(h2f, eu[k]), wh[k], ev, false);
                a = fmaf(__int_as_float(m.y), fmaxf(xv + ev, 0.f), a);
            }
            accv[ln] = a;
        }
    }

    float rootj = root_l[j], gmj = gamma_l[j] * BNS, btj = beta_l[j];
    #pragma unroll
    for (int ln = 0; ln < ANODES; ln++) {
        int n = n0 + ln;
        float v = accv[ln] + fmaxf(xn[ln] + rootj, 0.f) * invdeg[n];
        v = v * gmj + btj;
        if (relu) v = fmaxf(v, 0.f);
        if (vn_next) v += vn_next[(size_t)gid[n] * H_ + j];
        h_bf[(size_t)n * KP_ + swzcol(n, j)] = f2b(v);
    }
}

// ---------------- launch ----------------
extern "C" void kernel_launch(void* const* d_in, const int* in_sizes, int n_in,
                              void* d_out, int out_size, void* d_ws, size_t ws_size,
                              hipStream_t stream) {
    const int* node_types = (const int*)d_in[0];
    const int* src        = (const int*)d_in[1];
    const int* dst        = (const int*)d_in[2];
    const int* graph_ids  = (const int*)d_in[3];
    const float* edge_feats = (const float*)d_in[4];
    const float* node_emb   = (const float*)d_in[5];
    const float* Wn   = (const float*)d_in[6];
    const float* bn   = (const float*)d_in[7];
    const float* We   = (const float*)d_in[8];
    const float* be   = (const float*)d_in[9];
    const float* root = (const float*)d_in[10];
    const float* gamma = (const float*)d_in[11];
    const float* beta  = (const float*)d_in[12];
    const float* vn_emb = (const float*)d_in[13];
    const float* W1  = (const float*)d_in[14];
    const float* b1  = (const float*)d_in[15];
    const float* g1  = (const float*)d_in[16];
    const float* be1 = (const float*)d_in[17];
    const float* W2  = (const float*)d_in[18];
    const float* b2  = (const float*)d_in[19];
    const float* g2  = (const float*)d_in[20];
    const float* be2 = (const float*)d_in[21];
    const float* pW  = (const float*)d_in[22];
    const float* pb  = (const float*)d_in[23];
    float* out = (float*)d_out;

    // workspace carve-up (~155 MB; R1 proved >=253 MB available)
    char* p = (char*)d_ws;
    auto alloc = [&](size_t bytes) { void* q = (void*)p; p += (bytes + 255) & ~(size_t)255; return q; };
    ushort_t* h_bf   = (ushort_t*)alloc((size_t)MPAD * KP_ * 2);        // 64 MB (swizzled)
    ushort_t* x_bf   = (ushort_t*)alloc((size_t)MPAD * KP_ * 2);        // 64 MB (linear)
    ushort_t* ef16   = (ushort_t*)alloc((size_t)E_ * 16 * 2);           // 12.8 MB (f16 CSR)
    ushort_t* WnT    = (ushort_t*)alloc((size_t)L_ * 384 * KP_ * 2);
    unsigned* Weh    = (unsigned*)alloc((size_t)L_ * 8 * H_ * 4);
    ushort_t* W1T    = (ushort_t*)alloc((size_t)4 * 640 * KP_ * 2);
    ushort_t* W2T    = (ushort_t*)alloc((size_t)4 * 384 * 640 * 2);
    ushort_t* vtmp_bf= (ushort_t*)alloc((size_t)B_ * KP_ * 2);
    ushort_t* z_bf   = (ushort_t*)alloc((size_t)B_ * 640 * 2);
    float* vn    = (float*)alloc((size_t)B_ * H_ * 4);
    float* nrm   = (float*)alloc((size_t)N_ * 4);
    float* invdeg= (float*)alloc((size_t)N_ * 4);
    int* degi    = (int*)alloc((size_t)N_ * 4);
    int* csr_off = (int*)alloc((size_t)(N_ + 1) * 4);
    int* cursor  = (int*)alloc((size_t)N_ * 4);
    int2* meta   = (int2*)alloc((size_t)E_ * 8);
    int* rs      = (int*)alloc((size_t)(B_ + 1) * 4);
    int* partial = (int*)alloc((size_t)128 * 4);

    const int SCAN_NB = (N_ + 1023) / 1024;  // 98

    // degree histogram + norms
    hipMemsetAsync(degi, 0, (size_t)N_ * 4, stream);
    k_hist<<<(E_ + 255) / 256, 256, 0, stream>>>(dst, degi, E_);
    k_norm<<<(N_ + 255) / 256, 256, 0, stream>>>(degi, nrm, invdeg, N_);

    // CSR offsets = exclusive scan of degi
    k_scan1<<<SCAN_NB, 1024, 0, stream>>>(degi, csr_off, partial, N_);
    k_scan2<<<1, 128, 0, stream>>>(partial, SCAN_NB, csr_off + N_);
    k_scan3<<<SCAN_NB, 1024, 0, stream>>>(csr_off, partial, N_);
    hipMemcpyAsync(cursor, csr_off, (size_t)N_ * 4, hipMemcpyDeviceToDevice, stream);
    k_scatter<<<(E_ + 255) / 256, 256, 0, stream>>>(dst, src, edge_feats, nrm,
                                                    cursor, meta, ef16, E_);

    // graph segment boundaries (graph_ids sorted)
    k_rowstart<<<(B_ + 1 + 255) / 256, 256, 0, stream>>>(graph_ids, rs, N_, B_);

    // weights -> bf16 transposed swizzled; We -> packed half2
    k_convW<<<(L_ * 384 * (KP_ / 8) + 255) / 256, 256, 0, stream>>>(Wn, WnT, L_, H_, H_, KP_, 384);
    k_convWeh<<<(L_ * 8 * H_ + 255) / 256, 256, 0, stream>>>(We, Weh);
    k_convW<<<(4 * 640 * (KP_ / 8) + 255) / 256, 256, 0, stream>>>(W1, W1T, 4, H_, 2 * H_, KP_, 640);
    k_convW<<<(4 * 384 * (640 / 8) + 255) / 256, 256, 0, stream>>>(W2, W2T, 4, 2 * H_, H_, 640, 384);

    // h = node_emb[nt] + vn_emb (pads zeroed); vn = vn_emb
    k_hinit<<<N_, 320, 0, stream>>>(node_types, node_emb, vn_emb, h_bf);
    k_vninit<<<B_, 320, 0, stream>>>(vn_emb, vn);

    dim3 gx(3, MPAD / MB);    // x GEMM: n-blocks x m-blocks (A-panel L2 reuse)
    dim3 gz(5, B_ / MB);      // z GEMM: 5 x 16
    dim3 gv(3, B_ / MB);      // vn GEMM: 3 x 16
    for (int l = 0; l < L_; l++) {
        // x = h @ Wn[l] + bn[l]  -> bf16 LINEAR
        k_bgemm<<<gx, 256, 0, stream>>>(h_bf, WnT + (size_t)l * 384 * KP_,
                                        N_, H_, KP_,
                                        bn + (size_t)l * H_, nullptr, nullptr, 0,
                                        nullptr, 0, x_bf, KP_, 0);
        if (l < L_ - 1) {
            k_vtmp<<<B_, 256, 0, stream>>>(h_bf, vn, rs, vtmp_bf);
            // z = relu(bn1(vtmp @ W1 + b1)) -> bf16 swizzled [B][640]
            k_bgemm<<<gz, 256, 0, stream>>>(vtmp_bf, W1T + (size_t)l * 640 * KP_,
                                            B_, 2 * H_, KP_,
                                            b1 + (size_t)l * 2 * H_,
                                            g1 + (size_t)l * 2 * H_, be1 + (size_t)l * 2 * H_, 1,
                                            nullptr, 0, z_bf, 640, 1);
            // vn = relu(bn2(z @ W2 + b2)) -> fp32 [B][300]
            k_bgemm<<<gv, 256, 0, stream>>>(z_bf, W2T + (size_t)l * 384 * 640,
                                            B_, H_, 640,
                                            b2 + (size_t)l * H_,
                                            g2 + (size_t)l * H_, be2 + (size_t)l * H_, 1,
                                            vn, H_, nullptr, 0, 0);
        }
        // h = bn(agg + relu(x+root)*invdeg) (+relu/+vn_next if l<L-1)
        k_agg<<<N_ / ANODES, 320, 0, stream>>>(x_bf, h_bf, csr_off, meta, ef16,
                                               Weh + (size_t)l * 8 * H_, be + (size_t)l * H_,
                                               invdeg,
                                               root + (size_t)l * H_,
                                               gamma + (size_t)l * H_, beta + (size_t)l * H_,
                                               (l < L_ - 1) ? vn : nullptr, graph_ids,
                                               (l < L_ - 1) ? 1 : 0);
    }

    // fused readout: gmean -> head
    k_readout<<<B_, 256, 0, stream>>>(h_bf, rs, pW, pb, out);
}

// Round 16
// 1749.349 us; speedup vs baseline: 1.0689x; 1.0689x over previous
//
#include <hip/hip_runtime.h>
#include <hip/hip_bf16.h>
#include <hip/hip_fp16.h>

// Problem constants (fixed by the reference)
#define N_ 100000
#define MPAD 100096          // 782 * 128
#define E_ 400000
#define B_ 2048
#define H_ 300
#define KP_ 320              // H padded to mult of 32
#define L_ 5
#define EF_ 16
#define T_ 128
#define ANODES 8             // nodes per k_agg block (12500 blocks) — best measured (R14)
#define EMAX 128             // LDS-staged edge capacity per block
#define BNS 0.9999950000374997f  // 1/sqrt(1+1e-5)

typedef unsigned short ushort_t;
typedef short bf16x8 __attribute__((ext_vector_type(8)));
typedef float f32x4 __attribute__((ext_vector_type(4)));
typedef _Float16 h2f __attribute__((ext_vector_type(2)));

__device__ __forceinline__ ushort_t f2b(float v) {
    unsigned u = __float_as_uint(v);
    unsigned r = (u + 0x7FFFu + ((u >> 16) & 1u)) >> 16;
    return (ushort_t)r;
}

__device__ __forceinline__ float b2f(ushort_t u) {
    return __uint_as_float(((unsigned)u) << 16);
}

__device__ __forceinline__ void gl_lds16(const void* g, void* l) {
    __builtin_amdgcn_global_load_lds(
        (const __attribute__((address_space(1))) void*)g,
        (__attribute__((address_space(3))) void*)l, 16, 0, 0);
}

// swizzled column for logical (row r, col j) in a swizzled bf16 buffer
__device__ __forceinline__ int swzcol(int r, int j) {
    int u = ((j >> 3) & 3) ^ ((r >> 1) & 3);
    return (j & ~31) | (u << 3) | (j & 7);
}

// ---------------- CSR build ----------------
__global__ void k_hist(const int* __restrict__ dst, int* __restrict__ degi, int E) {
    int e = blockIdx.x * blockDim.x + threadIdx.x;
    if (e < E) atomicAdd(&degi[dst[e]], 1);
}

__global__ void k_norm(const int* __restrict__ degi, float* __restrict__ nrm,
                       float* __restrict__ invdeg, int N) {
    int n = blockIdx.x * blockDim.x + threadIdx.x;
    if (n < N) {
        float d = (float)degi[n] + 1.0f;
        nrm[n] = 1.0f / sqrtf(d);
        invdeg[n] = 1.0f / d;
    }
}

__global__ void k_scan1(const int* __restrict__ in, int* __restrict__ out,
                        int* __restrict__ partial, int N) {
    __shared__ int s[1024];
    int i = blockIdx.x * 1024 + threadIdx.x;
    int v = (i < N) ? in[i] : 0;
    s[threadIdx.x] = v;
    __syncthreads();
    for (int off = 1; off < 1024; off <<= 1) {
        int t = (threadIdx.x >= off) ? s[threadIdx.x - off] : 0;
        __syncthreads();
        s[threadIdx.x] += t;
        __syncthreads();
    }
    if (i < N) out[i] = s[threadIdx.x] - v;  // exclusive
    if (threadIdx.x == 1023) partial[blockIdx.x] = s[1023];
}

__global__ void k_scan2(int* __restrict__ partial, int nb, int* __restrict__ totalOut) {
    __shared__ int sh[128];
    int t = threadIdx.x;
    int v = (t < nb) ? partial[t] : 0;
    sh[t] = v;
    __syncthreads();
    for (int off = 1; off < 128; off <<= 1) {
        int u = (t >= off) ? sh[t - off] : 0;
        __syncthreads();
        sh[t] += u;
        __syncthreads();
    }
    if (t < nb) partial[t] = sh[t] - v;  // exclusive
    if (t == 127) *totalOut = sh[127];
}

__global__ void k_scan3(int* __restrict__ out, const int* __restrict__ partial, int N) {
    int i = blockIdx.x * 1024 + threadIdx.x;
    if (i < N) out[i] += partial[blockIdx.x];
}

// scatter edges into CSR order; meta = (src*KP_, en bits); f16 edge feats
__global__ void k_scatter(const int* __restrict__ dst, const int* __restrict__ src,
                          const float* __restrict__ ef, const float* __restrict__ nrm,
                          int* __restrict__ cursor, int2* __restrict__ meta,
                          ushort_t* __restrict__ ef16, int E) {
    int e = blockIdx.x * blockDim.x + threadIdx.x;
    if (e >= E) return;
    int d = dst[e], s = src[e];
    int pos = atomicAdd(&cursor[d], 1);
    int2 md;
    md.x = s * KP_;
    md.y = __float_as_int(nrm[s] * nrm[d]);
    meta[pos] = md;
    const float4* ep = (const float4*)&ef[(size_t)e * EF_];
    float4 e0 = ep[0], e1 = ep[1], e2 = ep[2], e3 = ep[3];
    uint4 ua, ub;
    ua.x = __builtin_bit_cast(unsigned, __floats2half2_rn(e0.x, e0.y));
    ua.y = __builtin_bit_cast(unsigned, __floats2half2_rn(e0.z, e0.w));
    ua.z = __builtin_bit_cast(unsigned, __floats2half2_rn(e1.x, e1.y));
    ua.w = __builtin_bit_cast(unsigned, __floats2half2_rn(e1.z, e1.w));
    ub.x = __builtin_bit_cast(unsigned, __floats2half2_rn(e2.x, e2.y));
    ub.y = __builtin_bit_cast(unsigned, __floats2half2_rn(e2.z, e2.w));
    ub.z = __builtin_bit_cast(unsigned, __floats2half2_rn(e3.x, e3.y));
    ub.w = __builtin_bit_cast(unsigned, __floats2half2_rn(e3.z, e3.w));
    uint4* op = (uint4*)&ef16[(size_t)pos * 16];
    op[0] = ua; op[1] = ub;
}

__global__ void k_rowstart(const int* __restrict__ gid, int* __restrict__ rs, int N, int B) {
    int b = blockIdx.x * blockDim.x + threadIdx.x;
    if (b <= B) {
        int lo = 0, hi = N;
        while (lo < hi) { int mid = (lo + hi) >> 1; if (gid[mid] < b) lo = mid + 1; else hi = mid; }
        rs[b] = lo;
    }
}

// ---------------- init ----------------
// writes ALL 320 cols (pad cols = 0) so later vector reads of pads are safe
__global__ void k_hinit(const int* __restrict__ nt, const float* __restrict__ emb,
                        const float* __restrict__ vn_emb,
                        ushort_t* __restrict__ h_bf) {
    int n = blockIdx.x; int j = threadIdx.x;
    if (j >= KP_) return;
    float v = (j < H_) ? emb[(size_t)nt[n] * H_ + j] + vn_emb[j] : 0.f;
    h_bf[(size_t)n * KP_ + swzcol(n, j)] = f2b(v);
}

__global__ void k_vninit(const float* __restrict__ vn_emb, float* __restrict__ vn) {
    int b = blockIdx.x; int j = threadIdx.x;
    if (j >= H_) return;
    vn[(size_t)b * H_ + j] = vn_emb[j];
}

// weight conversion: WT[l][n][k] = W[l][k][n], bf16, zero-padded, row-swizzled
__global__ void k_convW(const float* __restrict__ W, ushort_t* __restrict__ WT,
                        int nl, int K, int Nout, int KPv, int NPBv) {
    int UPR = KPv / 8;
    int tot = nl * NPBv * UPR;
    int idx = blockIdx.x * 256 + threadIdx.x;
    if (idx >= tot) return;
    int l = idx / (NPBv * UPR); int r = idx % (NPBv * UPR);
    int n = r / UPR; int ku = r % UPR;
    int k0 = ku * 8;
    int swz = (ku & 3) ^ ((n >> 1) & 3);
    size_t d = ((size_t)l * NPBv + n) * KPv + (size_t)(k0 & ~31) + swz * 8;
    #pragma unroll
    for (int i = 0; i < 8; i++) {
        int k = k0 + i;
        float v = (k < K && n < Nout) ? W[((size_t)l * K + k) * Nout + n] : 0.f;
        WT[d + i] = f2b(v);
    }
}

// We -> packed half2 pairs: Weh[l][k2][j] = (We[l][2k2][j], We[l][2k2+1][j])
__global__ void k_convWeh(const float* __restrict__ We, unsigned* __restrict__ Weh) {
    int idx = blockIdx.x * 256 + threadIdx.x;
    if (idx >= L_ * 8 * H_) return;
    int l = idx / (8 * H_); int r = idx % (8 * H_);
    int k2 = r / H_; int j = r % H_;
    float a = We[((size_t)l * EF_ + 2 * k2) * H_ + j];
    float b = We[((size_t)l * EF_ + 2 * k2 + 1) * H_ + j];
    Weh[((size_t)l * 8 + k2) * H_ + j] = __builtin_bit_cast(unsigned, __floats2half2_rn(a, b));
}

// ---------------- unified bf16 MFMA GEMM ----------------
// blockIdx.x = N-block (few), blockIdx.y = M-block (many): consecutive blocks
// share the same A panel via L2.
#define MB 128
#define NB 128
__launch_bounds__(256)
__global__ void k_bgemm(const ushort_t* __restrict__ A, const ushort_t* __restrict__ BT,
                        int M, int Nn, int KP,
                        const float* __restrict__ bias, const float* __restrict__ scale,
                        const float* __restrict__ shift, int relu,
                        float* __restrict__ Cf, int ldf,
                        ushort_t* __restrict__ Cb, int ldb, int swzout) {
    __shared__ ushort_t As[MB * 32];
    __shared__ ushort_t Bs[NB * 32];
    int tid = threadIdx.x;
    int lane = tid & 63, wid = tid >> 6;
    int wm = wid >> 1, wn = wid & 1;
    int m0 = blockIdx.y * MB, n0 = blockIdx.x * NB;
    f32x4 acc[4][4];
    #pragma unroll
    for (int mi = 0; mi < 4; mi++)
        #pragma unroll
        for (int ni = 0; ni < 4; ni++)
            acc[mi][ni] = (f32x4){0.f, 0.f, 0.f, 0.f};

    const ushort_t* Ab = A + (size_t)m0 * KP;
    const ushort_t* Bb = BT + (size_t)n0 * KP;
    int lr = lane & 15, lg = lane >> 4;

    for (int k0 = 0; k0 < KP; k0 += 32) {
        #pragma unroll
        for (int i = 0; i < 2; i++) {
            int li = tid + 256 * i;
            int r = li >> 2, u = li & 3;
            gl_lds16(Ab + (size_t)r * KP + k0 + u * 8, &As[(size_t)(li & ~63) * 8]);
        }
        #pragma unroll
        for (int i = 0; i < 2; i++) {
            int li = tid + 256 * i;
            int r = li >> 2, u = li & 3;
            gl_lds16(Bb + (size_t)r * KP + k0 + u * 8, &Bs[(size_t)(li & ~63) * 8]);
        }
        __syncthreads();
        bf16x8 af[4], bv[4];
        #pragma unroll
        for (int mi = 0; mi < 4; mi++) {
            int rr = wm * 64 + mi * 16 + lr;
            int uu = lg ^ ((rr >> 1) & 3);
            af[mi] = *(const bf16x8*)&As[rr * 32 + uu * 8];
        }
        #pragma unroll
        for (int ni = 0; ni < 4; ni++) {
            int rr = wn * 64 + ni * 16 + lr;
            int uu = lg ^ ((rr >> 1) & 3);
            bv[ni] = *(const bf16x8*)&Bs[rr * 32 + uu * 8];
        }
        #pragma unroll
        for (int mi = 0; mi < 4; mi++)
            #pragma unroll
            for (int ni = 0; ni < 4; ni++)
                acc[mi][ni] = __builtin_amdgcn_mfma_f32_16x16x32_bf16(
                    af[mi], bv[ni], acc[mi][ni], 0, 0, 0);
        __syncthreads();
    }

    #pragma unroll
    for (int ni = 0; ni < 4; ni++) {
        int gn = n0 + wn * 64 + ni * 16 + lr;
        if (gn >= Nn) continue;
        float bvv = bias[gn];
        float sc = scale ? scale[gn] * BNS : 0.f;
        float sh = shift ? shift[gn] : 0.f;
        #pragma unroll
        for (int mi = 0; mi < 4; mi++) {
            #pragma unroll
            for (int t = 0; t < 4; t++) {
                int gm = m0 + wm * 64 + mi * 16 + lg * 4 + t;
                if (gm >= M) continue;
                float v = acc[mi][ni][t] + bvv;
                if (scale) v = v * sc + sh;
                if (relu) v = fmaxf(v, 0.f);
                if (Cf) Cf[(size_t)gm * ldf + gn] = v;
                else    Cb[(size_t)gm * ldb + (swzout ? swzcol(gm, gn) : gn)] = f2b(v);
            }
        }
    }
}

// ---------------- vectorized per-graph segment sum -> vtmp (swizzled bf16) ----------------
__launch_bounds__(256)
__global__ void k_vtmp(const ushort_t* __restrict__ h_bf, const float* __restrict__ vn,
                       const int* __restrict__ rs, ushort_t* __restrict__ vtmp_bf) {
    __shared__ float red[40 * 8 * 6];
    int b = blockIdx.x;
    int t = threadIdx.x;
    int u = t % 40, rr = t / 40;
    int s = rs[b], e = rs[b + 1];
    if (rr < 6) {
        float a8[8] = {0.f, 0.f, 0.f, 0.f, 0.f, 0.f, 0.f, 0.f};
        int g = u >> 2, w = u & 3;
        for (int n = s + rr; n < e; n += 6) {
            int phys = (g << 2) | (w ^ ((n >> 1) & 3));
            bf16x8 hv = *(const bf16x8*)&h_bf[(size_t)n * KP_ + phys * 8];
            #pragma unroll
            for (int k = 0; k < 8; k++) a8[k] += b2f((ushort_t)hv[k]);
        }
        #pragma unroll
        for (int k = 0; k < 8; k++) red[(u * 8 + k) * 6 + rr] = a8[k];
    }
    __syncthreads();
    if (t < 40) {
        int g = t >> 2, w = t & 3;
        int phys = (g << 2) | (w ^ ((b >> 1) & 3));
        ushort_t ov[8];
        #pragma unroll
        for (int k = 0; k < 8; k++) {
            int j = t * 8 + k;
            float sum = 0.f;
            #pragma unroll
            for (int r = 0; r < 6; r++) sum += red[(t * 8 + k) * 6 + r];
            float val = (j < H_) ? sum + vn[(size_t)b * H_ + j] : 0.f;
            ov[k] = f2b(val);
        }
        *(bf16x8*)&vtmp_bf[(size_t)b * KP_ + phys * 8] = *(bf16x8*)ov;
    }
}

// ---------------- vectorized fused readout: gmean -> head ----------------
__launch_bounds__(256)
__global__ void k_readout(const ushort_t* __restrict__ h_bf, const int* __restrict__ rs,
                          const float* __restrict__ pW, const float* __restrict__ pb,
                          float* __restrict__ out) {
    __shared__ float red[40 * 8 * 6];
    __shared__ float gg[320];
    int b = blockIdx.x;
    int t = threadIdx.x;
    int u = t % 40, rr = t / 40;
    int s = rs[b], e = rs[b + 1];
    if (rr < 6) {
        float a8[8] = {0.f, 0.f, 0.f, 0.f, 0.f, 0.f, 0.f, 0.f};
        int g = u >> 2, w = u & 3;
        for (int n = s + rr; n < e; n += 6) {
            int phys = (g << 2) | (w ^ ((n >> 1) & 3));
            bf16x8 hv = *(const bf16x8*)&h_bf[(size_t)n * KP_ + phys * 8];
            #pragma unroll
            for (int k = 0; k < 8; k++) a8[k] += b2f((ushort_t)hv[k]);
        }
        #pragma unroll
        for (int k = 0; k < 8; k++) red[(u * 8 + k) * 6 + rr] = a8[k];
    }
    __syncthreads();
    if (t < 40) {
        int cnt = e - s; if (cnt < 1) cnt = 1;
        float ic = 1.f / (float)cnt;
        #pragma unroll
        for (int k = 0; k < 8; k++) {
            float sum = 0.f;
            #pragma unroll
            for (int r = 0; r < 6; r++) sum += red[(t * 8 + k) * 6 + r];
            gg[t * 8 + k] = sum * ic;
        }
    }
    __syncthreads();
    if (t < T_) {
        float o = pb[t];
        #pragma unroll 4
        for (int k = 0; k < H_; k++) o = fmaf(gg[k], pW[(size_t)k * T_ + t], o);
        out[(size_t)b * T_ + t] = o;
    }
}

// ---------------- edge aggregation: 8 nodes/block, pair-interleaved streams ------------
__global__ void k_agg(const ushort_t* __restrict__ x_bf,
                      ushort_t* __restrict__ h_bf,
                      const int* __restrict__ off, const int2* __restrict__ meta,
                      const ushort_t* __restrict__ ef16,
                      const unsigned* __restrict__ Weh_l, const float* __restrict__ be_l,
                      const float* __restrict__ invdeg,
                      const float* __restrict__ root_l, const float* __restrict__ gamma_l,
                      const float* __restrict__ beta_l,
                      const float* __restrict__ vn_next, const int* __restrict__ gid,
                      int relu) {
    __shared__ int2 s_md[EMAX];
    __shared__ unsigned s_ef[EMAX * 8];
    int n0 = blockIdx.x * ANODES;
    int tid = threadIdx.x;
    int j = tid;

    int offv[ANODES + 1];
    #pragma unroll
    for (int k = 0; k <= ANODES; k++) offv[k] = off[n0 + k];
    int estart = offv[0], cnt = offv[ANODES] - estart;
    bool lds_ok = cnt <= EMAX;

    // stage edge metadata (coalesced; all threads)
    if (lds_ok) {
        const unsigned* efu = (const unsigned*)ef16;
        for (int t = tid; t < cnt; t += 320) s_md[t] = meta[estart + t];
        for (int uu = tid; uu < 8 * cnt; uu += 320)
            s_ef[uu] = efu[(size_t)estart * 8 + uu];
    }
    __syncthreads();

    if (j >= H_) return;
    h2f wh[8];
    #pragma unroll
    for (int k2 = 0; k2 < 8; k2++)
        wh[k2] = __builtin_bit_cast(h2f, Weh_l[k2 * H_ + j]);
    float bej = be_l[j];

    // self x loads for all nodes (independent, issued early)
    float xn[ANODES];
    #pragma unroll
    for (int ln = 0; ln < ANODES; ln++)
        xn[ln] = b2f(x_bf[(size_t)(n0 + ln) * KP_ + j]);

    float accv[ANODES];
    #pragma unroll
    for (int k = 0; k < ANODES; k++) accv[k] = 0.f;

    if (lds_ok) {
        // pairs of node streams interleaved: up to 8 gathers in flight per iteration
        #pragma unroll
        for (int lp = 0; lp < ANODES / 2; lp++) {
            int na = 2 * lp, nb = 2 * lp + 1;
            int ia = offv[na] - estart, ea = offv[na + 1] - estart;
            int ib = offv[nb] - estart, eb = offv[nb + 1] - estart;
            float aa = 0.f, ab = 0.f;
            while (ia < ea || ib < eb) {  // wave-uniform condition
                bool qa = ia < ea, qb = ib < eb;
                // ---- issue phase ----
                int a0 = 0, a1 = 0, a2 = 0, a3 = 0;
                float ena0 = 0.f, ena1 = 0.f, ena2 = 0.f, ena3 = 0.f;
                float xa0 = 0.f, xa1 = 0.f, xa2 = 0.f, xa3 = 0.f;
                if (qa) {
                    a0 = ia;
                    a1 = (ia + 1 < ea) ? ia + 1 : ea - 1;
                    a2 = (ia + 2 < ea) ? ia + 2 : ea - 1;
                    a3 = (ia + 3 < ea) ? ia + 3 : ea - 1;
                    int2 m0 = s_md[a0], m1 = s_md[a1], m2 = s_md[a2], m3 = s_md[a3];
                    ena0 = __int_as_float(m0.y);
                    ena1 = (ia + 1 < ea) ? __int_as_float(m1.y) : 0.f;
                    ena2 = (ia + 2 < ea) ? __int_as_float(m2.y) : 0.f;
                    ena3 = (ia + 3 < ea) ? __int_as_float(m3.y) : 0.f;
                    xa0 = b2f(x_bf[(size_t)m0.x + j]);
                    xa1 = b2f(x_bf[(size_t)m1.x + j]);
                    xa2 = b2f(x_bf[(size_t)m2.x + j]);
                    xa3 = b2f(x_bf[(size_t)m3.x + j]);
                }
                int b0 = 0, b1 = 0, b2 = 0, b3 = 0;
                float enb0 = 0.f, enb1 = 0.f, enb2 = 0.f, enb3 = 0.f;
                float xb0 = 0.f, xb1 = 0.f, xb2 = 0.f, xb3 = 0.f;
                if (qb) {
                    b0 = ib;
                    b1 = (ib + 1 < eb) ? ib + 1 : eb - 1;
                    b2 = (ib + 2 < eb) ? ib + 2 : eb - 1;
                    b3 = (ib + 3 < eb) ? ib + 3 : eb - 1;
                    int2 m0 = s_md[b0], m1 = s_md[b1], m2 = s_md[b2], m3 = s_md[b3];
                    enb0 = __int_as_float(m0.y);
                    enb1 = (ib + 1 < eb) ? __int_as_float(m1.y) : 0.f;
                    enb2 = (ib + 2 < eb) ? __int_as_float(m2.y) : 0.f;
                    enb3 = (ib + 3 < eb) ? __int_as_float(m3.y) : 0.f;
                    xb0 = b2f(x_bf[(size_t)m0.x + j]);
                    xb1 = b2f(x_bf[(size_t)m1.x + j]);
                    xb2 = b2f(x_bf[(size_t)m2.x + j]);
                    xb3 = b2f(x_bf[(size_t)m3.x + j]);
                }
                // ---- compute phase ----
                if (qa) {
                    const unsigned* p0 = &s_ef[a0 * 8];
                    const unsigned* p1 = &s_ef[a1 * 8];
                    const unsigned* p2 = &s_ef[a2 * 8];
                    const unsigned* p3 = &s_ef[a3 * 8];
                    float e0 = bej, e1 = bej, e2 = bej, e3 = bej;
                    #pragma unroll
                    for (int k = 0; k < 8; k++) {
                        e0 = __builtin_amdgcn_fdot2(__builtin_bit_cast(h2f, p0[k]), wh[k], e0, false);
                        e1 = __builtin_amdgcn_fdot2(__builtin_bit_cast(h2f, p1[k]), wh[k], e1, false);
                        e2 = __builtin_amdgcn_fdot2(__builtin_bit_cast(h2f, p2[k]), wh[k], e2, false);
                        e3 = __builtin_amdgcn_fdot2(__builtin_bit_cast(h2f, p3[k]), wh[k], e3, false);
                    }
                    aa = fmaf(ena0, fmaxf(xa0 + e0, 0.f), aa);
                    aa = fmaf(ena1, fmaxf(xa1 + e1, 0.f), aa);
                    aa = fmaf(ena2, fmaxf(xa2 + e2, 0.f), aa);
                    aa = fmaf(ena3, fmaxf(xa3 + e3, 0.f), aa);
                    ia += 4;
                }
                if (qb) {
                    const unsigned* p0 = &s_ef[b0 * 8];
                    const unsigned* p1 = &s_ef[b1 * 8];
                    const unsigned* p2 = &s_ef[b2 * 8];
                    const unsigned* p3 = &s_ef[b3 * 8];
                    float e0 = bej, e1 = bej, e2 = bej, e3 = bej;
                    #pragma unroll
                    for (int k = 0; k < 8; k++) {
                        e0 = __builtin_amdgcn_fdot2(__builtin_bit_cast(h2f, p0[k]), wh[k], e0, false);
                        e1 = __builtin_amdgcn_fdot2(__builtin_bit_cast(h2f, p1[k]), wh[k], e1, false);
                        e2 = __builtin_amdgcn_fdot2(__builtin_bit_cast(h2f, p2[k]), wh[k], e2, false);
                        e3 = __builtin_amdgcn_fdot2(__builtin_bit_cast(h2f, p3[k]), wh[k], e3, false);
                    }
                    ab = fmaf(enb0, fmaxf(xb0 + e0, 0.f), ab);
                    ab = fmaf(enb1, fmaxf(xb1 + e1, 0.f), ab);
                    ab = fmaf(enb2, fmaxf(xb2 + e2, 0.f), ab);
                    ab = fmaf(enb3, fmaxf(xb3 + e3, 0.f), ab);
                    ib += 4;
                }
            }
            accv[na] = aa;
            accv[nb] = ab;
        }
    } else {
        // rare fallback (cnt > EMAX): all-global path
        #pragma unroll
        for (int ln = 0; ln < ANODES; ln++) {
            int rel = offv[ln], rend = offv[ln + 1];
            float a = 0.f;
            for (int q = rel; q < rend; q++) {
                int2 m = meta[q];
                float xv = b2f(x_bf[(size_t)m.x + j]);
                const unsigned* eu = (const unsigned*)&ef16[(size_t)q * 16];
                float ev = bej;
                #pragma unroll
                for (int k = 0; k < 8; k++)
                    ev = __builtin_amdgcn_fdot2(__builtin_bit_cast(h2f, eu[k]), wh[k], ev, false);
                a = fmaf(__int_as_float(m.y), fmaxf(xv + ev, 0.f), a);
            }
            accv[ln] = a;
        }
    }

    float rootj = root_l[j], gmj = gamma_l[j] * BNS, btj = beta_l[j];
    #pragma unroll
    for (int ln = 0; ln < ANODES; ln++) {
        int n = n0 + ln;
        float v = accv[ln] + fmaxf(xn[ln] + rootj, 0.f) * invdeg[n];
        v = v * gmj + btj;
        if (relu) v = fmaxf(v, 0.f);
        if (vn_next) v += vn_next[(size_t)gid[n] * H_ + j];
        h_bf[(size_t)n * KP_ + swzcol(n, j)] = f2b(v);
    }
}

// ---------------- launch ----------------
extern "C" void kernel_launch(void* const* d_in, const int* in_sizes, int n_in,
                              void* d_out, int out_size, void* d_ws, size_t ws_size,
                              hipStream_t stream) {
    const int* node_types = (const int*)d_in[0];
    const int* src        = (const int*)d_in[1];
    const int* dst        = (const int*)d_in[2];
    const int* graph_ids  = (const int*)d_in[3];
    const float* edge_feats = (const float*)d_in[4];
    const float* node_emb   = (const float*)d_in[5];
    const float* Wn   = (const float*)d_in[6];
    const float* bn   = (const float*)d_in[7];
    const float* We   = (const float*)d_in[8];
    const float* be   = (const float*)d_in[9];
    const float* root = (const float*)d_in[10];
    const float* gamma = (const float*)d_in[11];
    const float* beta  = (const float*)d_in[12];
    const float* vn_emb = (const float*)d_in[13];
    const float* W1  = (const float*)d_in[14];
    const float* b1  = (const float*)d_in[15];
    const float* g1  = (const float*)d_in[16];
    const float* be1 = (const float*)d_in[17];
    const float* W2  = (const float*)d_in[18];
    const float* b2  = (const float*)d_in[19];
    const float* g2  = (const float*)d_in[20];
    const float* be2 = (const float*)d_in[21];
    const float* pW  = (const float*)d_in[22];
    const float* pb  = (const float*)d_in[23];
    float* out = (float*)d_out;

    // workspace carve-up (~155 MB; R1 proved >=253 MB available)
    char* p = (char*)d_ws;
    auto alloc = [&](size_t bytes) { void* q = (void*)p; p += (bytes + 255) & ~(size_t)255; return q; };
    ushort_t* h_bf   = (ushort_t*)alloc((size_t)MPAD * KP_ * 2);        // 64 MB (swizzled)
    ushort_t* x_bf   = (ushort_t*)alloc((size_t)MPAD * KP_ * 2);        // 64 MB (linear)
    ushort_t* ef16   = (ushort_t*)alloc((size_t)E_ * 16 * 2);           // 12.8 MB (f16 CSR)
    ushort_t* WnT    = (ushort_t*)alloc((size_t)L_ * 384 * KP_ * 2);
    unsigned* Weh    = (unsigned*)alloc((size_t)L_ * 8 * H_ * 4);
    ushort_t* W1T    = (ushort_t*)alloc((size_t)4 * 640 * KP_ * 2);
    ushort_t* W2T    = (ushort_t*)alloc((size_t)4 * 384 * 640 * 2);
    ushort_t* vtmp_bf= (ushort_t*)alloc((size_t)B_ * KP_ * 2);
    ushort_t* z_bf   = (ushort_t*)alloc((size_t)B_ * 640 * 2);
    float* vn    = (float*)alloc((size_t)B_ * H_ * 4);
    float* nrm   = (float*)alloc((size_t)N_ * 4);
    float* invdeg= (float*)alloc((size_t)N_ * 4);
    int* degi    = (int*)alloc((size_t)N_ * 4);
    int* csr_off = (int*)alloc((size_t)(N_ + 1) * 4);
    int* cursor  = (int*)alloc((size_t)N_ * 4);
    int2* meta   = (int2*)alloc((size_t)E_ * 8);
    int* rs      = (int*)alloc((size_t)(B_ + 1) * 4);
    int* partial = (int*)alloc((size_t)128 * 4);

    const int SCAN_NB = (N_ + 1023) / 1024;  // 98

    // degree histogram + norms
    hipMemsetAsync(degi, 0, (size_t)N_ * 4, stream);
    k_hist<<<(E_ + 255) / 256, 256, 0, stream>>>(dst, degi, E_);
    k_norm<<<(N_ + 255) / 256, 256, 0, stream>>>(degi, nrm, invdeg, N_);

    // CSR offsets = exclusive scan of degi
    k_scan1<<<SCAN_NB, 1024, 0, stream>>>(degi, csr_off, partial, N_);
    k_scan2<<<1, 128, 0, stream>>>(partial, SCAN_NB, csr_off + N_);
    k_scan3<<<SCAN_NB, 1024, 0, stream>>>(csr_off, partial, N_);
    hipMemcpyAsync(cursor, csr_off, (size_t)N_ * 4, hipMemcpyDeviceToDevice, stream);
    k_scatter<<<(E_ + 255) / 256, 256, 0, stream>>>(dst, src, edge_feats, nrm,
                                                    cursor, meta, ef16, E_);

    // graph segment boundaries (graph_ids sorted)
    k_rowstart<<<(B_ + 1 + 255) / 256, 256, 0, stream>>>(graph_ids, rs, N_, B_);

    // weights -> bf16 transposed swizzled; We -> packed half2
    k_convW<<<(L_ * 384 * (KP_ / 8) + 255) / 256, 256, 0, stream>>>(Wn, WnT, L_, H_, H_, KP_, 384);
    k_convWeh<<<(L_ * 8 * H_ + 255) / 256, 256, 0, stream>>>(We, Weh);
    k_convW<<<(4 * 640 * (KP_ / 8) + 255) / 256, 256, 0, stream>>>(W1, W1T, 4, H_, 2 * H_, KP_, 640);
    k_convW<<<(4 * 384 * (640 / 8) + 255) / 256, 256, 0, stream>>>(W2, W2T, 4, 2 * H_, H_, 640, 384);

    // h = node_emb[nt] + vn_emb (pads zeroed); vn = vn_emb
    k_hinit<<<N_, 320, 0, stream>>>(node_types, node_emb, vn_emb, h_bf);
    k_vninit<<<B_, 320, 0, stream>>>(vn_emb, vn);

    dim3 gx(3, MPAD / MB);    // x GEMM: n-blocks x m-blocks (A-panel L2 reuse)
    dim3 gz(5, B_ / MB);      // z GEMM
    dim3 gv(3, B_ / MB);      // vn GEMM
    for (int l = 0; l < L_; l++) {
        // x = h @ Wn[l] + bn[l]  -> bf16 LINEAR
        k_bgemm<<<gx, 256, 0, stream>>>(h_bf, WnT + (size_t)l * 384 * KP_,
                                        N_, H_, KP_,
                                        bn + (size_t)l * H_, nullptr, nullptr, 0,
                                        nullptr, 0, x_bf, KP_, 0);
        if (l < L_ - 1) {
            k_vtmp<<<B_, 256, 0, stream>>>(h_bf, vn, rs, vtmp_bf);
            // z = relu(bn1(vtmp @ W1 + b1)) -> bf16 swizzled [B][640]
            k_bgemm<<<gz, 256, 0, stream>>>(vtmp_bf, W1T + (size_t)l * 640 * KP_,
                                            B_, 2 * H_, KP_,
                                            b1 + (size_t)l * 2 * H_,
                                            g1 + (size_t)l * 2 * H_, be1 + (size_t)l * 2 * H_, 1,
                                            nullptr, 0, z_bf, 640, 1);
            // vn = relu(bn2(z @ W2 + b2)) -> fp32 [B][300]
            k_bgemm<<<gv, 256, 0, stream>>>(z_bf, W2T + (size_t)l * 384 * 640,
                                            B_, H_, 640,
                                            b2 + (size_t)l * H_,
                                            g2 + (size_t)l * H_, be2 + (size_t)l * H_, 1,
                                            vn, H_, nullptr, 0, 0);
        }
        // h = bn(agg + relu(x+root)*invdeg) (+relu/+vn_next if l<L-1)
        k_agg<<<N_ / ANODES, 320, 0, stream>>>(x_bf, h_bf, csr_off, meta, ef16,
                                               Weh + (size_t)l * 8 * H_, be + (size_t)l * H_,
                                               invdeg,
                                               root + (size_t)l * H_,
                                               gamma + (size_t)l * H_, beta + (size_t)l * H_,
                                               (l < L_ - 1) ? vn : nullptr, graph_ids,
                                               (l < L_ - 1) ? 1 : 0);
    }

    // fused readout: gmean -> head
    k_readout<<<B_, 256, 0, stream>>>(h_bf, rs, pW, pb, out);
}

// Round 17
// 1704.806 us; speedup vs baseline: 1.0968x; 1.0261x over previous
//
#include <hip/hip_runtime.h>
#include <hip/hip_bf16.h>
#include <hip/hip_fp16.h>

// Problem constants (fixed by the reference)
#define N_ 100000
#define MPAD 100096          // 782 * 128
#define E_ 400000
#define B_ 2048
#define H_ 300
#define KP_ 320              // H padded to mult of 32
#define L_ 5
#define EF_ 16
#define T_ 128
#define ANODES 4             // nodes per k_agg block (25000 blocks): 2 interleaved pairs
#define EMAX 64              // LDS-staged edge capacity per block
#define BNS 0.9999950000374997f  // 1/sqrt(1+1e-5)

typedef unsigned short ushort_t;
typedef short bf16x8 __attribute__((ext_vector_type(8)));
typedef float f32x4 __attribute__((ext_vector_type(4)));
typedef _Float16 h2f __attribute__((ext_vector_type(2)));

__device__ __forceinline__ ushort_t f2b(float v) {
    unsigned u = __float_as_uint(v);
    unsigned r = (u + 0x7FFFu + ((u >> 16) & 1u)) >> 16;
    return (ushort_t)r;
}

__device__ __forceinline__ float b2f(ushort_t u) {
    return __uint_as_float(((unsigned)u) << 16);
}

__device__ __forceinline__ void gl_lds16(const void* g, void* l) {
    __builtin_amdgcn_global_load_lds(
        (const __attribute__((address_space(1))) void*)g,
        (__attribute__((address_space(3))) void*)l, 16, 0, 0);
}

// swizzled column for logical (row r, col j) in a swizzled bf16 buffer
__device__ __forceinline__ int swzcol(int r, int j) {
    int u = ((j >> 3) & 3) ^ ((r >> 1) & 3);
    return (j & ~31) | (u << 3) | (j & 7);
}

// ---------------- CSR build ----------------
__global__ void k_hist(const int* __restrict__ dst, int* __restrict__ degi, int E) {
    int e = blockIdx.x * blockDim.x + threadIdx.x;
    if (e < E) atomicAdd(&degi[dst[e]], 1);
}

__global__ void k_norm(const int* __restrict__ degi, float* __restrict__ nrm,
                       float* __restrict__ invdeg, int N) {
    int n = blockIdx.x * blockDim.x + threadIdx.x;
    if (n < N) {
        float d = (float)degi[n] + 1.0f;
        nrm[n] = 1.0f / sqrtf(d);
        invdeg[n] = 1.0f / d;
    }
}

__global__ void k_scan1(const int* __restrict__ in, int* __restrict__ out,
                        int* __restrict__ partial, int N) {
    __shared__ int s[1024];
    int i = blockIdx.x * 1024 + threadIdx.x;
    int v = (i < N) ? in[i] : 0;
    s[threadIdx.x] = v;
    __syncthreads();
    for (int off = 1; off < 1024; off <<= 1) {
        int t = (threadIdx.x >= off) ? s[threadIdx.x - off] : 0;
        __syncthreads();
        s[threadIdx.x] += t;
        __syncthreads();
    }
    if (i < N) out[i] = s[threadIdx.x] - v;  // exclusive
    if (threadIdx.x == 1023) partial[blockIdx.x] = s[1023];
}

__global__ void k_scan2(int* __restrict__ partial, int nb, int* __restrict__ totalOut) {
    __shared__ int sh[128];
    int t = threadIdx.x;
    int v = (t < nb) ? partial[t] : 0;
    sh[t] = v;
    __syncthreads();
    for (int off = 1; off < 128; off <<= 1) {
        int u = (t >= off) ? sh[t - off] : 0;
        __syncthreads();
        sh[t] += u;
        __syncthreads();
    }
    if (t < nb) partial[t] = sh[t] - v;  // exclusive
    if (t == 127) *totalOut = sh[127];
}

__global__ void k_scan3(int* __restrict__ out, const int* __restrict__ partial, int N) {
    int i = blockIdx.x * 1024 + threadIdx.x;
    if (i < N) out[i] += partial[blockIdx.x];
}

// scatter edges into CSR order; meta = (src*KP_, en bits); f16 edge feats
__global__ void k_scatter(const int* __restrict__ dst, const int* __restrict__ src,
                          const float* __restrict__ ef, const float* __restrict__ nrm,
                          int* __restrict__ cursor, int2* __restrict__ meta,
                          ushort_t* __restrict__ ef16, int E) {
    int e = blockIdx.x * blockDim.x + threadIdx.x;
    if (e >= E) return;
    int d = dst[e], s = src[e];
    int pos = atomicAdd(&cursor[d], 1);
    int2 md;
    md.x = s * KP_;
    md.y = __float_as_int(nrm[s] * nrm[d]);
    meta[pos] = md;
    const float4* ep = (const float4*)&ef[(size_t)e * EF_];
    float4 e0 = ep[0], e1 = ep[1], e2 = ep[2], e3 = ep[3];
    uint4 ua, ub;
    ua.x = __builtin_bit_cast(unsigned, __floats2half2_rn(e0.x, e0.y));
    ua.y = __builtin_bit_cast(unsigned, __floats2half2_rn(e0.z, e0.w));
    ua.z = __builtin_bit_cast(unsigned, __floats2half2_rn(e1.x, e1.y));
    ua.w = __builtin_bit_cast(unsigned, __floats2half2_rn(e1.z, e1.w));
    ub.x = __builtin_bit_cast(unsigned, __floats2half2_rn(e2.x, e2.y));
    ub.y = __builtin_bit_cast(unsigned, __floats2half2_rn(e2.z, e2.w));
    ub.z = __builtin_bit_cast(unsigned, __floats2half2_rn(e3.x, e3.y));
    ub.w = __builtin_bit_cast(unsigned, __floats2half2_rn(e3.z, e3.w));
    uint4* op = (uint4*)&ef16[(size_t)pos * 16];
    op[0] = ua; op[1] = ub;
}

__global__ void k_rowstart(const int* __restrict__ gid, int* __restrict__ rs, int N, int B) {
    int b = blockIdx.x * blockDim.x + threadIdx.x;
    if (b <= B) {
        int lo = 0, hi = N;
        while (lo < hi) { int mid = (lo + hi) >> 1; if (gid[mid] < b) lo = mid + 1; else hi = mid; }
        rs[b] = lo;
    }
}

// ---------------- init ----------------
// writes ALL 320 cols (pad cols = 0) so later vector reads of pads are safe
__global__ void k_hinit(const int* __restrict__ nt, const float* __restrict__ emb,
                        const float* __restrict__ vn_emb,
                        ushort_t* __restrict__ h_bf) {
    int n = blockIdx.x; int j = threadIdx.x;
    if (j >= KP_) return;
    float v = (j < H_) ? emb[(size_t)nt[n] * H_ + j] + vn_emb[j] : 0.f;
    h_bf[(size_t)n * KP_ + swzcol(n, j)] = f2b(v);
}

__global__ void k_vninit(const float* __restrict__ vn_emb, float* __restrict__ vn) {
    int b = blockIdx.x; int j = threadIdx.x;
    if (j >= H_) return;
    vn[(size_t)b * H_ + j] = vn_emb[j];
}

// weight conversion: WT[l][n][k] = W[l][k][n], bf16, zero-padded, row-swizzled
__global__ void k_convW(const float* __restrict__ W, ushort_t* __restrict__ WT,
                        int nl, int K, int Nout, int KPv, int NPBv) {
    int UPR = KPv / 8;
    int tot = nl * NPBv * UPR;
    int idx = blockIdx.x * 256 + threadIdx.x;
    if (idx >= tot) return;
    int l = idx / (NPBv * UPR); int r = idx % (NPBv * UPR);
    int n = r / UPR; int ku = r % UPR;
    int k0 = ku * 8;
    int swz = (ku & 3) ^ ((n >> 1) & 3);
    size_t d = ((size_t)l * NPBv + n) * KPv + (size_t)(k0 & ~31) + swz * 8;
    #pragma unroll
    for (int i = 0; i < 8; i++) {
        int k = k0 + i;
        float v = (k < K && n < Nout) ? W[((size_t)l * K + k) * Nout + n] : 0.f;
        WT[d + i] = f2b(v);
    }
}

// We -> packed half2 pairs: Weh[l][k2][j] = (We[l][2k2][j], We[l][2k2+1][j])
__global__ void k_convWeh(const float* __restrict__ We, unsigned* __restrict__ Weh) {
    int idx = blockIdx.x * 256 + threadIdx.x;
    if (idx >= L_ * 8 * H_) return;
    int l = idx / (8 * H_); int r = idx % (8 * H_);
    int k2 = r / H_; int j = r % H_;
    float a = We[((size_t)l * EF_ + 2 * k2) * H_ + j];
    float b = We[((size_t)l * EF_ + 2 * k2 + 1) * H_ + j];
    Weh[((size_t)l * 8 + k2) * H_ + j] = __builtin_bit_cast(unsigned, __floats2half2_rn(a, b));
}

// ---------------- unified bf16 MFMA GEMM ----------------
#define MB 128
#define NB 128
__launch_bounds__(256)
__global__ void k_bgemm(const ushort_t* __restrict__ A, const ushort_t* __restrict__ BT,
                        int M, int Nn, int KP,
                        const float* __restrict__ bias, const float* __restrict__ scale,
                        const float* __restrict__ shift, int relu,
                        float* __restrict__ Cf, int ldf,
                        ushort_t* __restrict__ Cb, int ldb, int swzout) {
    __shared__ ushort_t As[MB * 32];
    __shared__ ushort_t Bs[NB * 32];
    int tid = threadIdx.x;
    int lane = tid & 63, wid = tid >> 6;
    int wm = wid >> 1, wn = wid & 1;
    int m0 = blockIdx.x * MB, n0 = blockIdx.y * NB;
    f32x4 acc[4][4];
    #pragma unroll
    for (int mi = 0; mi < 4; mi++)
        #pragma unroll
        for (int ni = 0; ni < 4; ni++)
            acc[mi][ni] = (f32x4){0.f, 0.f, 0.f, 0.f};

    const ushort_t* Ab = A + (size_t)m0 * KP;
    const ushort_t* Bb = BT + (size_t)n0 * KP;
    int lr = lane & 15, lg = lane >> 4;

    for (int k0 = 0; k0 < KP; k0 += 32) {
        #pragma unroll
        for (int i = 0; i < 2; i++) {
            int li = tid + 256 * i;
            int r = li >> 2, u = li & 3;
            gl_lds16(Ab + (size_t)r * KP + k0 + u * 8, &As[(size_t)(li & ~63) * 8]);
        }
        #pragma unroll
        for (int i = 0; i < 2; i++) {
            int li = tid + 256 * i;
            int r = li >> 2, u = li & 3;
            gl_lds16(Bb + (size_t)r * KP + k0 + u * 8, &Bs[(size_t)(li & ~63) * 8]);
        }
        __syncthreads();
        bf16x8 af[4], bv[4];
        #pragma unroll
        for (int mi = 0; mi < 4; mi++) {
            int rr = wm * 64 + mi * 16 + lr;
            int uu = lg ^ ((rr >> 1) & 3);
            af[mi] = *(const bf16x8*)&As[rr * 32 + uu * 8];
        }
        #pragma unroll
        for (int ni = 0; ni < 4; ni++) {
            int rr = wn * 64 + ni * 16 + lr;
            int uu = lg ^ ((rr >> 1) & 3);
            bv[ni] = *(const bf16x8*)&Bs[rr * 32 + uu * 8];
        }
        #pragma unroll
        for (int mi = 0; mi < 4; mi++)
            #pragma unroll
            for (int ni = 0; ni < 4; ni++)
                acc[mi][ni] = __builtin_amdgcn_mfma_f32_16x16x32_bf16(
                    af[mi], bv[ni], acc[mi][ni], 0, 0, 0);
        __syncthreads();
    }

    #pragma unroll
    for (int ni = 0; ni < 4; ni++) {
        int gn = n0 + wn * 64 + ni * 16 + lr;
        if (gn >= Nn) continue;
        float bvv = bias[gn];
        float sc = scale ? scale[gn] * BNS : 0.f;
        float sh = shift ? shift[gn] : 0.f;
        #pragma unroll
        for (int mi = 0; mi < 4; mi++) {
            #pragma unroll
            for (int t = 0; t < 4; t++) {
                int gm = m0 + wm * 64 + mi * 16 + lg * 4 + t;
                if (gm >= M) continue;
                float v = acc[mi][ni][t] + bvv;
                if (scale) v = v * sc + sh;
                if (relu) v = fmaxf(v, 0.f);
                if (Cf) Cf[(size_t)gm * ldf + gn] = v;
                else    Cb[(size_t)gm * ldb + (swzout ? swzcol(gm, gn) : gn)] = f2b(v);
            }
        }
    }
}

// ---------------- vectorized per-graph segment sum -> vtmp (swizzled bf16) ----------------
__launch_bounds__(256)
__global__ void k_vtmp(const ushort_t* __restrict__ h_bf, const float* __restrict__ vn,
                       const int* __restrict__ rs, ushort_t* __restrict__ vtmp_bf) {
    __shared__ float red[40 * 8 * 6];
    int b = blockIdx.x;
    int t = threadIdx.x;
    int u = t % 40, rr = t / 40;
    int s = rs[b], e = rs[b + 1];
    if (rr < 6) {
        float a8[8] = {0.f, 0.f, 0.f, 0.f, 0.f, 0.f, 0.f, 0.f};
        int g = u >> 2, w = u & 3;
        for (int n = s + rr; n < e; n += 6) {
            int phys = (g << 2) | (w ^ ((n >> 1) & 3));
            bf16x8 hv = *(const bf16x8*)&h_bf[(size_t)n * KP_ + phys * 8];
            #pragma unroll
            for (int k = 0; k < 8; k++) a8[k] += b2f((ushort_t)hv[k]);
        }
        #pragma unroll
        for (int k = 0; k < 8; k++) red[(u * 8 + k) * 6 + rr] = a8[k];
    }
    __syncthreads();
    if (t < 40) {
        int g = t >> 2, w = t & 3;
        int phys = (g << 2) | (w ^ ((b >> 1) & 3));
        ushort_t ov[8];
        #pragma unroll
        for (int k = 0; k < 8; k++) {
            int j = t * 8 + k;
            float sum = 0.f;
            #pragma unroll
            for (int r = 0; r < 6; r++) sum += red[(t * 8 + k) * 6 + r];
            float val = (j < H_) ? sum + vn[(size_t)b * H_ + j] : 0.f;
            ov[k] = f2b(val);
        }
        *(bf16x8*)&vtmp_bf[(size_t)b * KP_ + phys * 8] = *(bf16x8*)ov;
    }
}

// ---------------- vectorized fused readout: gmean -> head ----------------
__launch_bounds__(256)
__global__ void k_readout(const ushort_t* __restrict__ h_bf, const int* __restrict__ rs,
                          const float* __restrict__ pW, const float* __restrict__ pb,
                          float* __restrict__ out) {
    __shared__ float red[40 * 8 * 6];
    __shared__ float gg[320];
    int b = blockIdx.x;
    int t = threadIdx.x;
    int u = t % 40, rr = t / 40;
    int s = rs[b], e = rs[b + 1];
    if (rr < 6) {
        float a8[8] = {0.f, 0.f, 0.f, 0.f, 0.f, 0.f, 0.f, 0.f};
        int g = u >> 2, w = u & 3;
        for (int n = s + rr; n < e; n += 6) {
            int phys = (g << 2) | (w ^ ((n >> 1) & 3));
            bf16x8 hv = *(const bf16x8*)&h_bf[(size_t)n * KP_ + phys * 8];
            #pragma unroll
            for (int k = 0; k < 8; k++) a8[k] += b2f((ushort_t)hv[k]);
        }
        #pragma unroll
        for (int k = 0; k < 8; k++) red[(u * 8 + k) * 6 + rr] = a8[k];
    }
    __syncthreads();
    if (t < 40) {
        int cnt = e - s; if (cnt < 1) cnt = 1;
        float ic = 1.f / (float)cnt;
        #pragma unroll
        for (int k = 0; k < 8; k++) {
            float sum = 0.f;
            #pragma unroll
            for (int r = 0; r < 6; r++) sum += red[(t * 8 + k) * 6 + r];
            gg[t * 8 + k] = sum * ic;
        }
    }
    __syncthreads();
    if (t < T_) {
        float o = pb[t];
        #pragma unroll 4
        for (int k = 0; k < H_; k++) o = fmaf(gg[k], pW[(size_t)k * T_ + t], o);
        out[(size_t)b * T_ + t] = o;
    }
}

// ---------------- edge aggregation: 4 nodes/block, pair-interleaved streams ------------
__global__ void k_agg(const ushort_t* __restrict__ x_bf,
                      ushort_t* __restrict__ h_bf,
                      const int* __restrict__ off, const int2* __restrict__ meta,
                      const ushort_t* __restrict__ ef16,
                      const unsigned* __restrict__ Weh_l, const float* __restrict__ be_l,
                      const float* __restrict__ invdeg,
                      const float* __restrict__ root_l, const float* __restrict__ gamma_l,
                      const float* __restrict__ beta_l,
                      const float* __restrict__ vn_next, const int* __restrict__ gid,
                      int relu) {
    __shared__ int2 s_md[EMAX];
    __shared__ unsigned s_ef[EMAX * 8];
    int n0 = blockIdx.x * ANODES;
    int tid = threadIdx.x;
    int j = tid;

    int offv[ANODES + 1];
    #pragma unroll
    for (int k = 0; k <= ANODES; k++) offv[k] = off[n0 + k];
    int estart = offv[0], cnt = offv[ANODES] - estart;
    bool lds_ok = cnt <= EMAX;

    // stage edge metadata (coalesced; all threads)
    if (lds_ok) {
        const unsigned* efu = (const unsigned*)ef16;
        for (int t = tid; t < cnt; t += 320) s_md[t] = meta[estart + t];
        for (int uu = tid; uu < 8 * cnt; uu += 320)
            s_ef[uu] = efu[(size_t)estart * 8 + uu];
    }
    __syncthreads();

    if (j >= H_) return;
    h2f wh[8];
    #pragma unroll
    for (int k2 = 0; k2 < 8; k2++)
        wh[k2] = __builtin_bit_cast(h2f, Weh_l[k2 * H_ + j]);
    float bej = be_l[j];

    // self x loads for all nodes (independent, issued early)
    float xn[ANODES];
    #pragma unroll
    for (int ln = 0; ln < ANODES; ln++)
        xn[ln] = b2f(x_bf[(size_t)(n0 + ln) * KP_ + j]);

    float accv[ANODES];
    #pragma unroll
    for (int k = 0; k < ANODES; k++) accv[k] = 0.f;

    if (lds_ok) {
        // pairs of node streams interleaved: up to 8 gathers in flight per iteration
        #pragma unroll
        for (int lp = 0; lp < ANODES / 2; lp++) {
            int na = 2 * lp, nb = 2 * lp + 1;
            int ia = offv[na] - estart, ea = offv[na + 1] - estart;
            int ib = offv[nb] - estart, eb = offv[nb + 1] - estart;
            float aa = 0.f, ab = 0.f;
            while (ia < ea || ib < eb) {  // wave-uniform condition
                bool qa = ia < ea, qb = ib < eb;
                // ---- issue phase ----
                int a0 = 0, a1 = 0, a2 = 0, a3 = 0;
                float ena0 = 0.f, ena1 = 0.f, ena2 = 0.f, ena3 = 0.f;
                float xa0 = 0.f, xa1 = 0.f, xa2 = 0.f, xa3 = 0.f;
                if (qa) {
                    a0 = ia;
                    a1 = (ia + 1 < ea) ? ia + 1 : ea - 1;
                    a2 = (ia + 2 < ea) ? ia + 2 : ea - 1;
                    a3 = (ia + 3 < ea) ? ia + 3 : ea - 1;
                    int2 m0 = s_md[a0], m1 = s_md[a1], m2 = s_md[a2], m3 = s_md[a3];
                    ena0 = __int_as_float(m0.y);
                    ena1 = (ia + 1 < ea) ? __int_as_float(m1.y) : 0.f;
                    ena2 = (ia + 2 < ea) ? __int_as_float(m2.y) : 0.f;
                    ena3 = (ia + 3 < ea) ? __int_as_float(m3.y) : 0.f;
                    xa0 = b2f(x_bf[(size_t)m0.x + j]);
                    xa1 = b2f(x_bf[(size_t)m1.x + j]);
                    xa2 = b2f(x_bf[(size_t)m2.x + j]);
                    xa3 = b2f(x_bf[(size_t)m3.x + j]);
                }
                int b0 = 0, b1 = 0, b2 = 0, b3 = 0;
                float enb0 = 0.f, enb1 = 0.f, enb2 = 0.f, enb3 = 0.f;
                float xb0 = 0.f, xb1 = 0.f, xb2 = 0.f, xb3 = 0.f;
                if (qb) {
                    b0 = ib;
                    b1 = (ib + 1 < eb) ? ib + 1 : eb - 1;
                    b2 = (ib + 2 < eb) ? ib + 2 : eb - 1;
                    b3 = (ib + 3 < eb) ? ib + 3 : eb - 1;
                    int2 m0 = s_md[b0], m1 = s_md[b1], m2 = s_md[b2], m3 = s_md[b3];
                    enb0 = __int_as_float(m0.y);
                    enb1 = (ib + 1 < eb) ? __int_as_float(m1.y) : 0.f;
                    enb2 = (ib + 2 < eb) ? __int_as_float(m2.y) : 0.f;
                    enb3 = (ib + 3 < eb) ? __int_as_float(m3.y) : 0.f;
                    xb0 = b2f(x_bf[(size_t)m0.x + j]);
                    xb1 = b2f(x_bf[(size_t)m1.x + j]);
                    xb2 = b2f(x_bf[(size_t)m2.x + j]);
                    xb3 = b2f(x_bf[(size_t)m3.x + j]);
                }
                // ---- compute phase ----
                if (qa) {
                    const unsigned* p0 = &s_ef[a0 * 8];
                    const unsigned* p1 = &s_ef[a1 * 8];
                    const unsigned* p2 = &s_ef[a2 * 8];
                    const unsigned* p3 = &s_ef[a3 * 8];
                    float e0 = bej, e1 = bej, e2 = bej, e3 = bej;
                    #pragma unroll
                    for (int k = 0; k < 8; k++) {
                        e0 = __builtin_amdgcn_fdot2(__builtin_bit_cast(h2f, p0[k]), wh[k], e0, false);
                        e1 = __builtin_amdgcn_fdot2(__builtin_bit_cast(h2f, p1[k]), wh[k], e1, false);
                        e2 = __builtin_amdgcn_fdot2(__builtin_bit_cast(h2f, p2[k]), wh[k], e2, false);
                        e3 = __builtin_amdgcn_fdot2(__builtin_bit_cast(h2f, p3[k]), wh[k], e3, false);
                    }
                    aa = fmaf(ena0, fmaxf(xa0 + e0, 0.f), aa);
                    aa = fmaf(ena1, fmaxf(xa1 + e1, 0.f), aa);
                    aa = fmaf(ena2, fmaxf(xa2 + e2, 0.f), aa);
                    aa = fmaf(ena3, fmaxf(xa3 + e3, 0.f), aa);
                    ia += 4;
                }
                if (qb) {
                    const unsigned* p0 = &s_ef[b0 * 8];
                    const unsigned* p1 = &s_ef[b1 * 8];
                    const unsigned* p2 = &s_ef[b2 * 8];
                    const unsigned* p3 = &s_ef[b3 * 8];
                    float e0 = bej, e1 = bej, e2 = bej, e3 = bej;
                    #pragma unroll
                    for (int k = 0; k < 8; k++) {
                        e0 = __builtin_amdgcn_fdot2(__builtin_bit_cast(h2f, p0[k]), wh[k], e0, false);
                        e1 = __builtin_amdgcn_fdot2(__builtin_bit_cast(h2f, p1[k]), wh[k], e1, false);
                        e2 = __builtin_amdgcn_fdot2(__builtin_bit_cast(h2f, p2[k]), wh[k], e2, false);
                        e3 = __builtin_amdgcn_fdot2(__builtin_bit_cast(h2f, p3[k]), wh[k], e3, false);
                    }
                    ab = fmaf(enb0, fmaxf(xb0 + e0, 0.f), ab);
                    ab = fmaf(enb1, fmaxf(xb1 + e1, 0.f), ab);
                    ab = fmaf(enb2, fmaxf(xb2 + e2, 0.f), ab);
                    ab = fmaf(enb3, fmaxf(xb3 + e3, 0.f), ab);
                    ib += 4;
                }
            }
            accv[na] = aa;
            accv[nb] = ab;
        }
    } else {
        // rare fallback (cnt > EMAX): all-global path
        #pragma unroll
        for (int ln = 0; ln < ANODES; ln++) {
            int rel = offv[ln], rend = offv[ln + 1];
            float a = 0.f;
            for (int q = rel; q < rend; q++) {
                int2 m = meta[q];
                float xv = b2f(x_bf[(size_t)m.x + j]);
                const unsigned* eu = (const unsigned*)&ef16[(size_t)q * 16];
                float ev = bej;
                #pragma unroll
                for (int k = 0; k < 8; k++)
                    ev = __builtin_amdgcn_fdot2(__builtin_bit_cast(h2f, eu[k]), wh[k], ev, false);
                a = fmaf(__int_as_float(m.y), fmaxf(xv + ev, 0.f), a);
            }
            accv[ln] = a;
        }
    }

    float rootj = root_l[j], gmj = gamma_l[j] * BNS, btj = beta_l[j];
    #pragma unroll
    for (int ln = 0; ln < ANODES; ln++) {
        int n = n0 + ln;
        float v = accv[ln] + fmaxf(xn[ln] + rootj, 0.f) * invdeg[n];
        v = v * gmj + btj;
        if (relu) v = fmaxf(v, 0.f);
        if (vn_next) v += vn_next[(size_t)gid[n] * H_ + j];
        h_bf[(size_t)n * KP_ + swzcol(n, j)] = f2b(v);
    }
}

// ---------------- launch ----------------
extern "C" void kernel_launch(void* const* d_in, const int* in_sizes, int n_in,
                              void* d_out, int out_size, void* d_ws, size_t ws_size,
                              hipStream_t stream) {
    const int* node_types = (const int*)d_in[0];
    const int* src        = (const int*)d_in[1];
    const int* dst        = (const int*)d_in[2];
    const int* graph_ids  = (const int*)d_in[3];
    const float* edge_feats = (const float*)d_in[4];
    const float* node_emb   = (const float*)d_in[5];
    const float* Wn   = (const float*)d_in[6];
    const float* bn   = (const float*)d_in[7];
    const float* We   = (const float*)d_in[8];
    const float* be   = (const float*)d_in[9];
    const float* root = (const float*)d_in[10];
    const float* gamma = (const float*)d_in[11];
    const float* beta  = (const float*)d_in[12];
    const float* vn_emb = (const float*)d_in[13];
    const float* W1  = (const float*)d_in[14];
    const float* b1  = (const float*)d_in[15];
    const float* g1  = (const float*)d_in[16];
    const float* be1 = (const float*)d_in[17];
    const float* W2  = (const float*)d_in[18];
    const float* b2  = (const float*)d_in[19];
    const float* g2  = (const float*)d_in[20];
    const float* be2 = (const float*)d_in[21];
    const float* pW  = (const float*)d_in[22];
    const float* pb  = (const float*)d_in[23];
    float* out = (float*)d_out;

    // workspace carve-up (~155 MB; R1 proved >=253 MB available)
    char* p = (char*)d_ws;
    auto alloc = [&](size_t bytes) { void* q = (void*)p; p += (bytes + 255) & ~(size_t)255; return q; };
    ushort_t* h_bf   = (ushort_t*)alloc((size_t)MPAD * KP_ * 2);        // 64 MB (swizzled)
    ushort_t* x_bf   = (ushort_t*)alloc((size_t)MPAD * KP_ * 2);        // 64 MB (linear)
    ushort_t* ef16   = (ushort_t*)alloc((size_t)E_ * 16 * 2);           // 12.8 MB (f16 CSR)
    ushort_t* WnT    = (ushort_t*)alloc((size_t)L_ * 384 * KP_ * 2);
    unsigned* Weh    = (unsigned*)alloc((size_t)L_ * 8 * H_ * 4);
    ushort_t* W1T    = (ushort_t*)alloc((size_t)4 * 640 * KP_ * 2);
    ushort_t* W2T    = (ushort_t*)alloc((size_t)4 * 384 * 640 * 2);
    ushort_t* vtmp_bf= (ushort_t*)alloc((size_t)B_ * KP_ * 2);
    ushort_t* z_bf   = (ushort_t*)alloc((size_t)B_ * 640 * 2);
    float* vn    = (float*)alloc((size_t)B_ * H_ * 4);
    float* nrm   = (float*)alloc((size_t)N_ * 4);
    float* invdeg= (float*)alloc((size_t)N_ * 4);
    int* degi    = (int*)alloc((size_t)N_ * 4);
    int* csr_off = (int*)alloc((size_t)(N_ + 1) * 4);
    int* cursor  = (int*)alloc((size_t)N_ * 4);
    int2* meta   = (int2*)alloc((size_t)E_ * 8);
    int* rs      = (int*)alloc((size_t)(B_ + 1) * 4);
    int* partial = (int*)alloc((size_t)128 * 4);

    const int SCAN_NB = (N_ + 1023) / 1024;  // 98

    // degree histogram + norms
    hipMemsetAsync(degi, 0, (size_t)N_ * 4, stream);
    k_hist<<<(E_ + 255) / 256, 256, 0, stream>>>(dst, degi, E_);
    k_norm<<<(N_ + 255) / 256, 256, 0, stream>>>(degi, nrm, invdeg, N_);

    // CSR offsets = exclusive scan of degi
    k_scan1<<<SCAN_NB, 1024, 0, stream>>>(degi, csr_off, partial, N_);
    k_scan2<<<1, 128, 0, stream>>>(partial, SCAN_NB, csr_off + N_);
    k_scan3<<<SCAN_NB, 1024, 0, stream>>>(csr_off, partial, N_);
    hipMemcpyAsync(cursor, csr_off, (size_t)N_ * 4, hipMemcpyDeviceToDevice, stream);
    k_scatter<<<(E_ + 255) / 256, 256, 0, stream>>>(dst, src, edge_feats, nrm,
                                                    cursor, meta, ef16, E_);

    // graph segment boundaries (graph_ids sorted)
    k_rowstart<<<(B_ + 1 + 255) / 256, 256, 0, stream>>>(graph_ids, rs, N_, B_);

    // weights -> bf16 transposed swizzled; We -> packed half2
    k_convW<<<(L_ * 384 * (KP_ / 8) + 255) / 256, 256, 0, stream>>>(Wn, WnT, L_, H_, H_, KP_, 384);
    k_convWeh<<<(L_ * 8 * H_ + 255) / 256, 256, 0, stream>>>(We, Weh);
    k_convW<<<(4 * 640 * (KP_ / 8) + 255) / 256, 256, 0, stream>>>(W1, W1T, 4, H_, 2 * H_, KP_, 640);
    k_convW<<<(4 * 384 * (640 / 8) + 255) / 256, 256, 0, stream>>>(W2, W2T, 4, 2 * H_, H_, 640, 384);

    // h = node_emb[nt] + vn_emb (pads zeroed); vn = vn_emb
    k_hinit<<<N_, 320, 0, stream>>>(node_types, node_emb, vn_emb, h_bf);
    k_vninit<<<B_, 320, 0, stream>>>(vn_emb, vn);

    dim3 gx(MPAD / MB, 3);    // x GEMM (R14 order — measured best)
    dim3 gz(B_ / MB, 5);      // z GEMM
    dim3 gv(B_ / MB, 3);      // vn GEMM
    for (int l = 0; l < L_; l++) {
        // x = h @ Wn[l] + bn[l]  -> bf16 LINEAR
        k_bgemm<<<gx, 256, 0, stream>>>(h_bf, WnT + (size_t)l * 384 * KP_,
                                        N_, H_, KP_,
                                        bn + (size_t)l * H_, nullptr, nullptr, 0,
                                        nullptr, 0, x_bf, KP_, 0);
        if (l < L_ - 1) {
            k_vtmp<<<B_, 256, 0, stream>>>(h_bf, vn, rs, vtmp_bf);
            // z = relu(bn1(vtmp @ W1 + b1)) -> bf16 swizzled [B][640]
            k_bgemm<<<gz, 256, 0, stream>>>(vtmp_bf, W1T + (size_t)l * 640 * KP_,
                                            B_, 2 * H_, KP_,
                                            b1 + (size_t)l * 2 * H_,
                                            g1 + (size_t)l * 2 * H_, be1 + (size_t)l * 2 * H_, 1,
                                            nullptr, 0, z_bf, 640, 1);
            // vn = relu(bn2(z @ W2 + b2)) -> fp32 [B][300]
            k_bgemm<<<gv, 256, 0, stream>>>(z_bf, W2T + (size_t)l * 384 * 640,
                                            B_, H_, 640,
                                            b2 + (size_t)l * H_,
                                            g2 + (size_t)l * H_, be2 + (size_t)l * H_, 1,
                                            vn, H_, nullptr, 0, 0);
        }
        // h = bn(agg + relu(x+root)*invdeg) (+relu/+vn_next if l<L-1)
        k_agg<<<N_ / ANODES, 320, 0, stream>>>(x_bf, h_bf, csr_off, meta, ef16,
                                               Weh + (size_t)l * 8 * H_, be + (size_t)l * H_,
                                               invdeg,
                                               root + (size_t)l * H_,
                                               gamma + (size_t)l * H_, beta + (size_t)l * H_,
                                               (l < L_ - 1) ? vn : nullptr, graph_ids,
                                               (l < L_ - 1) ? 1 : 0);
    }

    // fused readout: gmean -> head
    k_readout<<<B_, 256, 0, stream>>>(h_bf, rs, pW, pb, out);
}

// Round 18
// 1606.153 us; speedup vs baseline: 1.1642x; 1.0614x over previous
//
#include <hip/hip_runtime.h>
#include <hip/hip_bf16.h>
#include <hip/hip_fp16.h>

// Problem constants (fixed by the reference)
#define N_ 100000
#define MPAD 100096          // 782 * 128
#define E_ 400000
#define B_ 2048
#define H_ 300
#define KP_ 320              // H padded to mult of 32
#define L_ 5
#define EF_ 16
#define T_ 128
#define ANODES 4             // nodes per k_agg block (25000 blocks): 2 interleaved pairs
#define EMAX 64              // LDS-staged edge capacity per block
#define BNS 0.9999950000374997f  // 1/sqrt(1+1e-5)

typedef unsigned short ushort_t;
typedef short bf16x8 __attribute__((ext_vector_type(8)));
typedef float f32x4 __attribute__((ext_vector_type(4)));
typedef _Float16 h2f __attribute__((ext_vector_type(2)));

__device__ __forceinline__ ushort_t f2b(float v) {
    unsigned u = __float_as_uint(v);
    unsigned r = (u + 0x7FFFu + ((u >> 16) & 1u)) >> 16;
    return (ushort_t)r;
}

__device__ __forceinline__ float b2f(ushort_t u) {
    return __uint_as_float(((unsigned)u) << 16);
}

__device__ __forceinline__ void gl_lds16(const void* g, void* l) {
    __builtin_amdgcn_global_load_lds(
        (const __attribute__((address_space(1))) void*)g,
        (__attribute__((address_space(3))) void*)l, 16, 0, 0);
}

// swizzled column for logical (row r, col j) in a swizzled bf16 buffer
__device__ __forceinline__ int swzcol(int r, int j) {
    int u = ((j >> 3) & 3) ^ ((r >> 1) & 3);
    return (j & ~31) | (u << 3) | (j & 7);
}

// ---------------- CSR build ----------------
__global__ void k_hist(const int* __restrict__ dst, int* __restrict__ degi, int E) {
    int e = blockIdx.x * blockDim.x + threadIdx.x;
    if (e < E) atomicAdd(&degi[dst[e]], 1);
}

__global__ void k_norm(const int* __restrict__ degi, float* __restrict__ nrm,
                       float* __restrict__ invdeg, int N) {
    int n = blockIdx.x * blockDim.x + threadIdx.x;
    if (n < N) {
        float d = (float)degi[n] + 1.0f;
        nrm[n] = 1.0f / sqrtf(d);
        invdeg[n] = 1.0f / d;
    }
}

__global__ void k_scan1(const int* __restrict__ in, int* __restrict__ out,
                        int* __restrict__ partial, int N) {
    __shared__ int s[1024];
    int i = blockIdx.x * 1024 + threadIdx.x;
    int v = (i < N) ? in[i] : 0;
    s[threadIdx.x] = v;
    __syncthreads();
    for (int off = 1; off < 1024; off <<= 1) {
        int t = (threadIdx.x >= off) ? s[threadIdx.x - off] : 0;
        __syncthreads();
        s[threadIdx.x] += t;
        __syncthreads();
    }
    if (i < N) out[i] = s[threadIdx.x] - v;  // exclusive
    if (threadIdx.x == 1023) partial[blockIdx.x] = s[1023];
}

__global__ void k_scan2(int* __restrict__ partial, int nb, int* __restrict__ totalOut) {
    __shared__ int sh[128];
    int t = threadIdx.x;
    int v = (t < nb) ? partial[t] : 0;
    sh[t] = v;
    __syncthreads();
    for (int off = 1; off < 128; off <<= 1) {
        int u = (t >= off) ? sh[t - off] : 0;
        __syncthreads();
        sh[t] += u;
        __syncthreads();
    }
    if (t < nb) partial[t] = sh[t] - v;  // exclusive
    if (t == 127) *totalOut = sh[127];
}

__global__ void k_scan3(int* __restrict__ out, const int* __restrict__ partial, int N) {
    int i = blockIdx.x * 1024 + threadIdx.x;
    if (i < N) out[i] += partial[blockIdx.x];
}

// scatter edges into CSR order; meta = (src*KP_, en bits); f16 edge feats
__global__ void k_scatter(const int* __restrict__ dst, const int* __restrict__ src,
                          const float* __restrict__ ef, const float* __restrict__ nrm,
                          int* __restrict__ cursor, int2* __restrict__ meta,
                          ushort_t* __restrict__ ef16, int E) {
    int e = blockIdx.x * blockDim.x + threadIdx.x;
    if (e >= E) return;
    int d = dst[e], s = src[e];
    int pos = atomicAdd(&cursor[d], 1);
    int2 md;
    md.x = s * KP_;
    md.y = __float_as_int(nrm[s] * nrm[d]);
    meta[pos] = md;
    const float4* ep = (const float4*)&ef[(size_t)e * EF_];
    float4 e0 = ep[0], e1 = ep[1], e2 = ep[2], e3 = ep[3];
    uint4 ua, ub;
    ua.x = __builtin_bit_cast(unsigned, __floats2half2_rn(e0.x, e0.y));
    ua.y = __builtin_bit_cast(unsigned, __floats2half2_rn(e0.z, e0.w));
    ua.z = __builtin_bit_cast(unsigned, __floats2half2_rn(e1.x, e1.y));
    ua.w = __builtin_bit_cast(unsigned, __floats2half2_rn(e1.z, e1.w));
    ub.x = __builtin_bit_cast(unsigned, __floats2half2_rn(e2.x, e2.y));
    ub.y = __builtin_bit_cast(unsigned, __floats2half2_rn(e2.z, e2.w));
    ub.z = __builtin_bit_cast(unsigned, __floats2half2_rn(e3.x, e3.y));
    ub.w = __builtin_bit_cast(unsigned, __floats2half2_rn(e3.z, e3.w));
    uint4* op = (uint4*)&ef16[(size_t)pos * 16];
    op[0] = ua; op[1] = ub;
}

__global__ void k_rowstart(const int* __restrict__ gid, int* __restrict__ rs, int N, int B) {
    int b = blockIdx.x * blockDim.x + threadIdx.x;
    if (b <= B) {
        int lo = 0, hi = N;
        while (lo < hi) { int mid = (lo + hi) >> 1; if (gid[mid] < b) lo = mid + 1; else hi = mid; }
        rs[b] = lo;
    }
}

// ---------------- init ----------------
// writes ALL 320 cols (pad cols = 0) so later vector reads of pads are safe
__global__ void k_hinit(const int* __restrict__ nt, const float* __restrict__ emb,
                        const float* __restrict__ vn_emb,
                        ushort_t* __restrict__ h_bf) {
    int n = blockIdx.x; int j = threadIdx.x;
    if (j >= KP_) return;
    float v = (j < H_) ? emb[(size_t)nt[n] * H_ + j] + vn_emb[j] : 0.f;
    h_bf[(size_t)n * KP_ + swzcol(n, j)] = f2b(v);
}

__global__ void k_vninit(const float* __restrict__ vn_emb, float* __restrict__ vn) {
    int b = blockIdx.x; int j = threadIdx.x;
    if (j >= H_) return;
    vn[(size_t)b * H_ + j] = vn_emb[j];
}

// weight conversion: WT[l][n][k] = W[l][k][n], bf16, zero-padded, row-swizzled
__global__ void k_convW(const float* __restrict__ W, ushort_t* __restrict__ WT,
                        int nl, int K, int Nout, int KPv, int NPBv) {
    int UPR = KPv / 8;
    int tot = nl * NPBv * UPR;
    int idx = blockIdx.x * 256 + threadIdx.x;
    if (idx >= tot) return;
    int l = idx / (NPBv * UPR); int r = idx % (NPBv * UPR);
    int n = r / UPR; int ku = r % UPR;
    int k0 = ku * 8;
    int swz = (ku & 3) ^ ((n >> 1) & 3);
    size_t d = ((size_t)l * NPBv + n) * KPv + (size_t)(k0 & ~31) + swz * 8;
    #pragma unroll
    for (int i = 0; i < 8; i++) {
        int k = k0 + i;
        float v = (k < K && n < Nout) ? W[((size_t)l * K + k) * Nout + n] : 0.f;
        WT[d + i] = f2b(v);
    }
}

// We -> packed half2 pairs: Weh[l][k2][j] = (We[l][2k2][j], We[l][2k2+1][j])
__global__ void k_convWeh(const float* __restrict__ We, unsigned* __restrict__ Weh) {
    int idx = blockIdx.x * 256 + threadIdx.x;
    if (idx >= L_ * 8 * H_) return;
    int l = idx / (8 * H_); int r = idx % (8 * H_);
    int k2 = r / H_; int j = r % H_;
    float a = We[((size_t)l * EF_ + 2 * k2) * H_ + j];
    float b = We[((size_t)l * EF_ + 2 * k2 + 1) * H_ + j];
    Weh[((size_t)l * 8 + k2) * H_ + j] = __builtin_bit_cast(unsigned, __floats2half2_rn(a, b));
}

// ---------------- unified bf16 MFMA GEMM (128x128 tile) ----------------
#define MB 128
#define NB 128
__launch_bounds__(256)
__global__ void k_bgemm(const ushort_t* __restrict__ A, const ushort_t* __restrict__ BT,
                        int M, int Nn, int KP,
                        const float* __restrict__ bias, const float* __restrict__ scale,
                        const float* __restrict__ shift, int relu,
                        float* __restrict__ Cf, int ldf,
                        ushort_t* __restrict__ Cb, int ldb, int swzout) {
    __shared__ ushort_t As[MB * 32];
    __shared__ ushort_t Bs[NB * 32];
    int tid = threadIdx.x;
    int lane = tid & 63, wid = tid >> 6;
    int wm = wid >> 1, wn = wid & 1;
    int m0 = blockIdx.x * MB, n0 = blockIdx.y * NB;
    f32x4 acc[4][4];
    #pragma unroll
    for (int mi = 0; mi < 4; mi++)
        #pragma unroll
        for (int ni = 0; ni < 4; ni++)
            acc[mi][ni] = (f32x4){0.f, 0.f, 0.f, 0.f};

    const ushort_t* Ab = A + (size_t)m0 * KP;
    const ushort_t* Bb = BT + (size_t)n0 * KP;
    int lr = lane & 15, lg = lane >> 4;

    for (int k0 = 0; k0 < KP; k0 += 32) {
        #pragma unroll
        for (int i = 0; i < 2; i++) {
            int li = tid + 256 * i;
            int r = li >> 2, u = li & 3;
            gl_lds16(Ab + (size_t)r * KP + k0 + u * 8, &As[(size_t)(li & ~63) * 8]);
        }
        #pragma unroll
        for (int i = 0; i < 2; i++) {
            int li = tid + 256 * i;
            int r = li >> 2, u = li & 3;
            gl_lds16(Bb + (size_t)r * KP + k0 + u * 8, &Bs[(size_t)(li & ~63) * 8]);
        }
        __syncthreads();
        bf16x8 af[4], bv[4];
        #pragma unroll
        for (int mi = 0; mi < 4; mi++) {
            int rr = wm * 64 + mi * 16 + lr;
            int uu = lg ^ ((rr >> 1) & 3);
            af[mi] = *(const bf16x8*)&As[rr * 32 + uu * 8];
        }
        #pragma unroll
        for (int ni = 0; ni < 4; ni++) {
            int rr = wn * 64 + ni * 16 + lr;
            int uu = lg ^ ((rr >> 1) & 3);
            bv[ni] = *(const bf16x8*)&Bs[rr * 32 + uu * 8];
        }
        #pragma unroll
        for (int mi = 0; mi < 4; mi++)
            #pragma unroll
            for (int ni = 0; ni < 4; ni++)
                acc[mi][ni] = __builtin_amdgcn_mfma_f32_16x16x32_bf16(
                    af[mi], bv[ni], acc[mi][ni], 0, 0, 0);
        __syncthreads();
    }

    #pragma unroll
    for (int ni = 0; ni < 4; ni++) {
        int gn = n0 + wn * 64 + ni * 16 + lr;
        if (gn >= Nn) continue;
        float bvv = bias[gn];
        float sc = scale ? scale[gn] * BNS : 0.f;
        float sh = shift ? shift[gn] : 0.f;
        #pragma unroll
        for (int mi = 0; mi < 4; mi++) {
            #pragma unroll
            for (int t = 0; t < 4; t++) {
                int gm = m0 + wm * 64 + mi * 16 + lg * 4 + t;
                if (gm >= M) continue;
                float v = acc[mi][ni][t] + bvv;
                if (scale) v = v * sc + sh;
                if (relu) v = fmaxf(v, 0.f);
                if (Cf) Cf[(size_t)gm * ldf + gn] = v;
                else    Cb[(size_t)gm * ldb + (swzout ? swzcol(gm, gn) : gn)] = f2b(v);
            }
        }
    }
}

// ---------------- small-tile bf16 MFMA GEMM (64x64, 4 waves) ----------------
// For the small vn-MLP GEMMs (M=2048): 4x the block count of the 128-tile,
// so all CUs get work. Same staging/swizzle/fragment conventions as k_bgemm.
__launch_bounds__(256)
__global__ void k_bgemm64(const ushort_t* __restrict__ A, const ushort_t* __restrict__ BT,
                          int M, int Nn, int KP,
                          const float* __restrict__ bias, const float* __restrict__ scale,
                          const float* __restrict__ shift, int relu,
                          float* __restrict__ Cf, int ldf,
                          ushort_t* __restrict__ Cb, int ldb, int swzout) {
    __shared__ ushort_t As[64 * 32];
    __shared__ ushort_t Bs[64 * 32];
    int tid = threadIdx.x;
    int lane = tid & 63, wid = tid >> 6;  // 4 waves; wave = 16 output rows
    int m0 = blockIdx.x * 64, n0 = blockIdx.y * 64;
    f32x4 acc[4];
    #pragma unroll
    for (int ni = 0; ni < 4; ni++) acc[ni] = (f32x4){0.f, 0.f, 0.f, 0.f};

    const ushort_t* Ab = A + (size_t)m0 * KP;
    const ushort_t* Bb = BT + (size_t)n0 * KP;
    int lr = lane & 15, lg = lane >> 4;
    int r = tid >> 2, u = tid & 3;  // 4 threads per row, 16B each (32 cols)

    for (int k0 = 0; k0 < KP; k0 += 32) {
        gl_lds16(Ab + (size_t)r * KP + k0 + u * 8, &As[(size_t)(tid & ~63) * 8]);
        gl_lds16(Bb + (size_t)r * KP + k0 + u * 8, &Bs[(size_t)(tid & ~63) * 8]);
        __syncthreads();
        int rrA = wid * 16 + lr;
        int uuA = lg ^ ((rrA >> 1) & 3);
        bf16x8 af = *(const bf16x8*)&As[rrA * 32 + uuA * 8];
        bf16x8 bv[4];
        #pragma unroll
        for (int ni = 0; ni < 4; ni++) {
            int rr = ni * 16 + lr;
            int uu = lg ^ ((rr >> 1) & 3);
            bv[ni] = *(const bf16x8*)&Bs[rr * 32 + uu * 8];
        }
        #pragma unroll
        for (int ni = 0; ni < 4; ni++)
            acc[ni] = __builtin_amdgcn_mfma_f32_16x16x32_bf16(af, bv[ni], acc[ni], 0, 0, 0);
        __syncthreads();
    }

    #pragma unroll
    for (int ni = 0; ni < 4; ni++) {
        int gn = n0 + ni * 16 + lr;
        if (gn >= Nn) continue;
        float bvv = bias[gn];
        float sc = scale ? scale[gn] * BNS : 0.f;
        float sh = shift ? shift[gn] : 0.f;
        #pragma unroll
        for (int t = 0; t < 4; t++) {
            int gm = m0 + wid * 16 + lg * 4 + t;
            if (gm >= M) continue;
            float v = acc[ni][t] + bvv;
            if (scale) v = v * sc + sh;
            if (relu) v = fmaxf(v, 0.f);
            if (Cf) Cf[(size_t)gm * ldf + gn] = v;
            else    Cb[(size_t)gm * ldb + (swzout ? swzcol(gm, gn) : gn)] = f2b(v);
        }
    }
}

// ---------------- vectorized per-graph segment sum -> vtmp (swizzled bf16) ----------------
__launch_bounds__(256)
__global__ void k_vtmp(const ushort_t* __restrict__ h_bf, const float* __restrict__ vn,
                       const int* __restrict__ rs, ushort_t* __restrict__ vtmp_bf) {
    __shared__ float red[40 * 8 * 6];
    int b = blockIdx.x;
    int t = threadIdx.x;
    int u = t % 40, rr = t / 40;
    int s = rs[b], e = rs[b + 1];
    if (rr < 6) {
        float a8[8] = {0.f, 0.f, 0.f, 0.f, 0.f, 0.f, 0.f, 0.f};
        int g = u >> 2, w = u & 3;
        for (int n = s + rr; n < e; n += 6) {
            int phys = (g << 2) | (w ^ ((n >> 1) & 3));
            bf16x8 hv = *(const bf16x8*)&h_bf[(size_t)n * KP_ + phys * 8];
            #pragma unroll
            for (int k = 0; k < 8; k++) a8[k] += b2f((ushort_t)hv[k]);
        }
        #pragma unroll
        for (int k = 0; k < 8; k++) red[(u * 8 + k) * 6 + rr] = a8[k];
    }
    __syncthreads();
    if (t < 40) {
        int g = t >> 2, w = t & 3;
        int phys = (g << 2) | (w ^ ((b >> 1) & 3));
        ushort_t ov[8];
        #pragma unroll
        for (int k = 0; k < 8; k++) {
            int j = t * 8 + k;
            float sum = 0.f;
            #pragma unroll
            for (int r = 0; r < 6; r++) sum += red[(t * 8 + k) * 6 + r];
            float val = (j < H_) ? sum + vn[(size_t)b * H_ + j] : 0.f;
            ov[k] = f2b(val);
        }
        *(bf16x8*)&vtmp_bf[(size_t)b * KP_ + phys * 8] = *(bf16x8*)ov;
    }
}

// ---------------- vectorized fused readout: gmean -> head ----------------
__launch_bounds__(256)
__global__ void k_readout(const ushort_t* __restrict__ h_bf, const int* __restrict__ rs,
                          const float* __restrict__ pW, const float* __restrict__ pb,
                          float* __restrict__ out) {
    __shared__ float red[40 * 8 * 6];
    __shared__ float gg[320];
    int b = blockIdx.x;
    int t = threadIdx.x;
    int u = t % 40, rr = t / 40;
    int s = rs[b], e = rs[b + 1];
    if (rr < 6) {
        float a8[8] = {0.f, 0.f, 0.f, 0.f, 0.f, 0.f, 0.f, 0.f};
        int g = u >> 2, w = u & 3;
        for (int n = s + rr; n < e; n += 6) {
            int phys = (g << 2) | (w ^ ((n >> 1) & 3));
            bf16x8 hv = *(const bf16x8*)&h_bf[(size_t)n * KP_ + phys * 8];
            #pragma unroll
            for (int k = 0; k < 8; k++) a8[k] += b2f((ushort_t)hv[k]);
        }
        #pragma unroll
        for (int k = 0; k < 8; k++) red[(u * 8 + k) * 6 + rr] = a8[k];
    }
    __syncthreads();
    if (t < 40) {
        int cnt = e - s; if (cnt < 1) cnt = 1;
        float ic = 1.f / (float)cnt;
        #pragma unroll
        for (int k = 0; k < 8; k++) {
            float sum = 0.f;
            #pragma unroll
            for (int r = 0; r < 6; r++) sum += red[(t * 8 + k) * 6 + r];
            gg[t * 8 + k] = sum * ic;
        }
    }
    __syncthreads();
    if (t < T_) {
        float o = pb[t];
        #pragma unroll 4
        for (int k = 0; k < H_; k++) o = fmaf(gg[k], pW[(size_t)k * T_ + t], o);
        out[(size_t)b * T_ + t] = o;
    }
}

// ---------------- edge aggregation: 4 nodes/block, pair-interleaved streams ------------
__global__ void k_agg(const ushort_t* __restrict__ x_bf,
                      ushort_t* __restrict__ h_bf,
                      const int* __restrict__ off, const int2* __restrict__ meta,
                      const ushort_t* __restrict__ ef16,
                      const unsigned* __restrict__ Weh_l, const float* __restrict__ be_l,
                      const float* __restrict__ invdeg,
                      const float* __restrict__ root_l, const float* __restrict__ gamma_l,
                      const float* __restrict__ beta_l,
                      const float* __restrict__ vn_next, const int* __restrict__ gid,
                      int relu) {
    __shared__ int2 s_md[EMAX];
    __shared__ unsigned s_ef[EMAX * 8];
    int n0 = blockIdx.x * ANODES;
    int tid = threadIdx.x;
    int j = tid;

    int offv[ANODES + 1];
    #pragma unroll
    for (int k = 0; k <= ANODES; k++) offv[k] = off[n0 + k];
    int estart = offv[0], cnt = offv[ANODES] - estart;
    bool lds_ok = cnt <= EMAX;

    // stage edge metadata (coalesced; all threads)
    if (lds_ok) {
        const unsigned* efu = (const unsigned*)ef16;
        for (int t = tid; t < cnt; t += 320) s_md[t] = meta[estart + t];
        for (int uu = tid; uu < 8 * cnt; uu += 320)
            s_ef[uu] = efu[(size_t)estart * 8 + uu];
    }
    __syncthreads();

    if (j >= H_) return;
    h2f wh[8];
    #pragma unroll
    for (int k2 = 0; k2 < 8; k2++)
        wh[k2] = __builtin_bit_cast(h2f, Weh_l[k2 * H_ + j]);
    float bej = be_l[j];

    // self x loads for all nodes (independent, issued early)
    float xn[ANODES];
    #pragma unroll
    for (int ln = 0; ln < ANODES; ln++)
        xn[ln] = b2f(x_bf[(size_t)(n0 + ln) * KP_ + j]);

    float accv[ANODES];
    #pragma unroll
    for (int k = 0; k < ANODES; k++) accv[k] = 0.f;

    if (lds_ok) {
        // pairs of node streams interleaved: up to 8 gathers in flight per iteration
        #pragma unroll
        for (int lp = 0; lp < ANODES / 2; lp++) {
            int na = 2 * lp, nb = 2 * lp + 1;
            int ia = offv[na] - estart, ea = offv[na + 1] - estart;
            int ib = offv[nb] - estart, eb = offv[nb + 1] - estart;
            float aa = 0.f, ab = 0.f;
            while (ia < ea || ib < eb) {  // wave-uniform condition
                bool qa = ia < ea, qb = ib < eb;
                // ---- issue phase ----
                int a0 = 0, a1 = 0, a2 = 0, a3 = 0;
                float ena0 = 0.f, ena1 = 0.f, ena2 = 0.f, ena3 = 0.f;
                float xa0 = 0.f, xa1 = 0.f, xa2 = 0.f, xa3 = 0.f;
                if (qa) {
                    a0 = ia;
                    a1 = (ia + 1 < ea) ? ia + 1 : ea - 1;
                    a2 = (ia + 2 < ea) ? ia + 2 : ea - 1;
                    a3 = (ia + 3 < ea) ? ia + 3 : ea - 1;
                    int2 m0 = s_md[a0], m1 = s_md[a1], m2 = s_md[a2], m3 = s_md[a3];
                    ena0 = __int_as_float(m0.y);
                    ena1 = (ia + 1 < ea) ? __int_as_float(m1.y) : 0.f;
                    ena2 = (ia + 2 < ea) ? __int_as_float(m2.y) : 0.f;
                    ena3 = (ia + 3 < ea) ? __int_as_float(m3.y) : 0.f;
                    xa0 = b2f(x_bf[(size_t)m0.x + j]);
                    xa1 = b2f(x_bf[(size_t)m1.x + j]);
                    xa2 = b2f(x_bf[(size_t)m2.x + j]);
                    xa3 = b2f(x_bf[(size_t)m3.x + j]);
                }
                int b0 = 0, b1 = 0, b2 = 0, b3 = 0;
                float enb0 = 0.f, enb1 = 0.f, enb2 = 0.f, enb3 = 0.f;
                float xb0 = 0.f, xb1 = 0.f, xb2 = 0.f, xb3 = 0.f;
                if (qb) {
                    b0 = ib;
                    b1 = (ib + 1 < eb) ? ib + 1 : eb - 1;
                    b2 = (ib + 2 < eb) ? ib + 2 : eb - 1;
                    b3 = (ib + 3 < eb) ? ib + 3 : eb - 1;
                    int2 m0 = s_md[b0], m1 = s_md[b1], m2 = s_md[b2], m3 = s_md[b3];
                    enb0 = __int_as_float(m0.y);
                    enb1 = (ib + 1 < eb) ? __int_as_float(m1.y) : 0.f;
                    enb2 = (ib + 2 < eb) ? __int_as_float(m2.y) : 0.f;
                    enb3 = (ib + 3 < eb) ? __int_as_float(m3.y) : 0.f;
                    xb0 = b2f(x_bf[(size_t)m0.x + j]);
                    xb1 = b2f(x_bf[(size_t)m1.x + j]);
                    xb2 = b2f(x_bf[(size_t)m2.x + j]);
                    xb3 = b2f(x_bf[(size_t)m3.x + j]);
                }
                // ---- compute phase ----
                if (qa) {
                    const unsigned* p0 = &s_ef[a0 * 8];
                    const unsigned* p1 = &s_ef[a1 * 8];
                    const unsigned* p2 = &s_ef[a2 * 8];
                    const unsigned* p3 = &s_ef[a3 * 8];
                    float e0 = bej, e1 = bej, e2 = bej, e3 = bej;
                    #pragma unroll
                    for (int k = 0; k < 8; k++) {
                        e0 = __builtin_amdgcn_fdot2(__builtin_bit_cast(h2f, p0[k]), wh[k], e0, false);
                        e1 = __builtin_amdgcn_fdot2(__builtin_bit_cast(h2f, p1[k]), wh[k], e1, false);
                        e2 = __builtin_amdgcn_fdot2(__builtin_bit_cast(h2f, p2[k]), wh[k], e2, false);
                        e3 = __builtin_amdgcn_fdot2(__builtin_bit_cast(h2f, p3[k]), wh[k], e3, false);
                    }
                    aa = fmaf(ena0, fmaxf(xa0 + e0, 0.f), aa);
                    aa = fmaf(ena1, fmaxf(xa1 + e1, 0.f), aa);
                    aa = fmaf(ena2, fmaxf(xa2 + e2, 0.f), aa);
                    aa = fmaf(ena3, fmaxf(xa3 + e3, 0.f), aa);
                    ia += 4;
                }
                if (qb) {
                    const unsigned* p0 = &s_ef[b0 * 8];
                    const unsigned* p1 = &s_ef[b1 * 8];
                    const unsigned* p2 = &s_ef[b2 * 8];
                    const unsigned* p3 = &s_ef[b3 * 8];
                    float e0 = bej, e1 = bej, e2 = bej, e3 = bej;
                    #pragma unroll
                    for (int k = 0; k < 8; k++) {
                        e0 = __builtin_amdgcn_fdot2(__builtin_bit_cast(h2f, p0[k]), wh[k], e0, false);
                        e1 = __builtin_amdgcn_fdot2(__builtin_bit_cast(h2f, p1[k]), wh[k], e1, false);
                        e2 = __builtin_amdgcn_fdot2(__builtin_bit_cast(h2f, p2[k]), wh[k], e2, false);
                        e3 = __builtin_amdgcn_fdot2(__builtin_bit_cast(h2f, p3[k]), wh[k], e3, false);
                    }
                    ab = fmaf(enb0, fmaxf(xb0 + e0, 0.f), ab);
                    ab = fmaf(enb1, fmaxf(xb1 + e1, 0.f), ab);
                    ab = fmaf(enb2, fmaxf(xb2 + e2, 0.f), ab);
                    ab = fmaf(enb3, fmaxf(xb3 + e3, 0.f), ab);
                    ib += 4;
                }
            }
            accv[na] = aa;
            accv[nb] = ab;
        }
    } else {
        // rare fallback (cnt > EMAX): all-global path
        #pragma unroll
        for (int ln = 0; ln < ANODES; ln++) {
            int rel = offv[ln], rend = offv[ln + 1];
            float a = 0.f;
            for (int q = rel; q < rend; q++) {
                int2 m = meta[q];
                float xv = b2f(x_bf[(size_t)m.x + j]);
                const unsigned* eu = (const unsigned*)&ef16[(size_t)q * 16];
                float ev = bej;
                #pragma unroll
                for (int k = 0; k < 8; k++)
                    ev = __builtin_amdgcn_fdot2(__builtin_bit_cast(h2f, eu[k]), wh[k], ev, false);
                a = fmaf(__int_as_float(m.y), fmaxf(xv + ev, 0.f), a);
            }
            accv[ln] = a;
        }
    }

    float rootj = root_l[j], gmj = gamma_l[j] * BNS, btj = beta_l[j];
    #pragma unroll
    for (int ln = 0; ln < ANODES; ln++) {
        int n = n0 + ln;
        float v = accv[ln] + fmaxf(xn[ln] + rootj, 0.f) * invdeg[n];
        v = v * gmj + btj;
        if (relu) v = fmaxf(v, 0.f);
        if (vn_next) v += vn_next[(size_t)gid[n] * H_ + j];
        h_bf[(size_t)n * KP_ + swzcol(n, j)] = f2b(v);
    }
}

// ---------------- launch ----------------
extern "C" void kernel_launch(void* const* d_in, const int* in_sizes, int n_in,
                              void* d_out, int out_size, void* d_ws, size_t ws_size,
                              hipStream_t stream) {
    const int* node_types = (const int*)d_in[0];
    const int* src        = (const int*)d_in[1];
    const int* dst        = (const int*)d_in[2];
    const int* graph_ids  = (const int*)d_in[3];
    const float* edge_feats = (const float*)d_in[4];
    const float* node_emb   = (const float*)d_in[5];
    const float* Wn   = (const float*)d_in[6];
    const float* bn   = (const float*)d_in[7];
    const float* We   = (const float*)d_in[8];
    const float* be   = (const float*)d_in[9];
    const float* root = (const float*)d_in[10];
    const float* gamma = (const float*)d_in[11];
    const float* beta  = (const float*)d_in[12];
    const float* vn_emb = (const float*)d_in[13];
    const float* W1  = (const float*)d_in[14];
    const float* b1  = (const float*)d_in[15];
    const float* g1  = (const float*)d_in[16];
    const float* be1 = (const float*)d_in[17];
    const float* W2  = (const float*)d_in[18];
    const float* b2  = (const float*)d_in[19];
    const float* g2  = (const float*)d_in[20];
    const float* be2 = (const float*)d_in[21];
    const float* pW  = (const float*)d_in[22];
    const float* pb  = (const float*)d_in[23];
    float* out = (float*)d_out;

    // workspace carve-up (~155 MB; R1 proved >=253 MB available)
    char* p = (char*)d_ws;
    auto alloc = [&](size_t bytes) { void* q = (void*)p; p += (bytes + 255) & ~(size_t)255; return q; };
    ushort_t* h_bf   = (ushort_t*)alloc((size_t)MPAD * KP_ * 2);        // 64 MB (swizzled)
    ushort_t* x_bf   = (ushort_t*)alloc((size_t)MPAD * KP_ * 2);        // 64 MB (linear)
    ushort_t* ef16   = (ushort_t*)alloc((size_t)E_ * 16 * 2);           // 12.8 MB (f16 CSR)
    ushort_t* WnT    = (ushort_t*)alloc((size_t)L_ * 384 * KP_ * 2);
    unsigned* Weh    = (unsigned*)alloc((size_t)L_ * 8 * H_ * 4);
    ushort_t* W1T    = (ushort_t*)alloc((size_t)4 * 640 * KP_ * 2);
    ushort_t* W2T    = (ushort_t*)alloc((size_t)4 * 384 * 640 * 2);
    ushort_t* vtmp_bf= (ushort_t*)alloc((size_t)B_ * KP_ * 2);
    ushort_t* z_bf   = (ushort_t*)alloc((size_t)B_ * 640 * 2);
    float* vn    = (float*)alloc((size_t)B_ * H_ * 4);
    float* nrm   = (float*)alloc((size_t)N_ * 4);
    float* invdeg= (float*)alloc((size_t)N_ * 4);
    int* degi    = (int*)alloc((size_t)N_ * 4);
    int* csr_off = (int*)alloc((size_t)(N_ + 1) * 4);
    int* cursor  = (int*)alloc((size_t)N_ * 4);
    int2* meta   = (int2*)alloc((size_t)E_ * 8);
    int* rs      = (int*)alloc((size_t)(B_ + 1) * 4);
    int* partial = (int*)alloc((size_t)128 * 4);

    const int SCAN_NB = (N_ + 1023) / 1024;  // 98

    // degree histogram + norms
    hipMemsetAsync(degi, 0, (size_t)N_ * 4, stream);
    k_hist<<<(E_ + 255) / 256, 256, 0, stream>>>(dst, degi, E_);
    k_norm<<<(N_ + 255) / 256, 256, 0, stream>>>(degi, nrm, invdeg, N_);

    // CSR offsets = exclusive scan of degi
    k_scan1<<<SCAN_NB, 1024, 0, stream>>>(degi, csr_off, partial, N_);
    k_scan2<<<1, 128, 0, stream>>>(partial, SCAN_NB, csr_off + N_);
    k_scan3<<<SCAN_NB, 1024, 0, stream>>>(csr_off, partial, N_);
    hipMemcpyAsync(cursor, csr_off, (size_t)N_ * 4, hipMemcpyDeviceToDevice, stream);
    k_scatter<<<(E_ + 255) / 256, 256, 0, stream>>>(dst, src, edge_feats, nrm,
                                                    cursor, meta, ef16, E_);

    // graph segment boundaries (graph_ids sorted)
    k_rowstart<<<(B_ + 1 + 255) / 256, 256, 0, stream>>>(graph_ids, rs, N_, B_);

    // weights -> bf16 transposed swizzled; We -> packed half2
    k_convW<<<(L_ * 384 * (KP_ / 8) + 255) / 256, 256, 0, stream>>>(Wn, WnT, L_, H_, H_, KP_, 384);
    k_convWeh<<<(L_ * 8 * H_ + 255) / 256, 256, 0, stream>>>(We, Weh);
    k_convW<<<(4 * 640 * (KP_ / 8) + 255) / 256, 256, 0, stream>>>(W1, W1T, 4, H_, 2 * H_, KP_, 640);
    k_convW<<<(4 * 384 * (640 / 8) + 255) / 256, 256, 0, stream>>>(W2, W2T, 4, 2 * H_, H_, 640, 384);

    // h = node_emb[nt] + vn_emb (pads zeroed); vn = vn_emb
    k_hinit<<<N_, 320, 0, stream>>>(node_types, node_emb, vn_emb, h_bf);
    k_vninit<<<B_, 320, 0, stream>>>(vn_emb, vn);

    dim3 gx(MPAD / MB, 3);        // x GEMM: 128-tile (2346 blocks)
    dim3 gz64(B_ / 64, 10);       // z GEMM: 64-tile, 320 blocks
    dim3 gv64(B_ / 64, 5);        // vn GEMM: 64-tile, 160 blocks
    for (int l = 0; l < L_; l++) {
        // x = h @ Wn[l] + bn[l]  -> bf16 LINEAR
        k_bgemm<<<gx, 256, 0, stream>>>(h_bf, WnT + (size_t)l * 384 * KP_,
                                        N_, H_, KP_,
                                        bn + (size_t)l * H_, nullptr, nullptr, 0,
                                        nullptr, 0, x_bf, KP_, 0);
        if (l < L_ - 1) {
            k_vtmp<<<B_, 256, 0, stream>>>(h_bf, vn, rs, vtmp_bf);
            // z = relu(bn1(vtmp @ W1 + b1)) -> bf16 swizzled [B][640]
            k_bgemm64<<<gz64, 256, 0, stream>>>(vtmp_bf, W1T + (size_t)l * 640 * KP_,
                                                B_, 2 * H_, KP_,
                                                b1 + (size_t)l * 2 * H_,
                                                g1 + (size_t)l * 2 * H_, be1 + (size_t)l * 2 * H_, 1,
                                                nullptr, 0, z_bf, 640, 1);
            // vn = relu(bn2(z @ W2 + b2)) -> fp32 [B][300]
            k_bgemm64<<<gv64, 256, 0, stream>>>(z_bf, W2T + (size_t)l * 384 * 640,
                                                B_, H_, 640,
                                                b2 + (size_t)l * H_,
                                                g2 + (size_t)l * H_, be2 + (size_t)l * H_, 1,
                                                vn, H_, nullptr, 0, 0);
        }
        // h = bn(agg + relu(x+root)*invdeg) (+relu/+vn_next if l<L-1)
        k_agg<<<N_ / ANODES, 320, 0, stream>>>(x_bf, h_bf, csr_off, meta, ef16,
                                               Weh + (size_t)l * 8 * H_, be + (size_t)l * H_,
                                               invdeg,
                                               root + (size_t)l * H_,
                                               gamma + (size_t)l * H_, beta + (size_t)l * H_,
                                               (l < L_ - 1) ? vn : nullptr, graph_ids,
                                               (l < L_ - 1) ? 1 : 0);
    }

    // fused readout: gmean -> head
    k_readout<<<B_, 256, 0, stream>>>(h_bf, rs, pW, pb, out);
}